// Round 11
// baseline (203.544 us; speedup 1.0000x reference)
//
#include <hip/hip_runtime.h>

typedef float          f32x4    __attribute__((ext_vector_type(4)));
typedef float          f32x2    __attribute__((ext_vector_type(2)));
typedef float          float8v  __attribute__((ext_vector_type(8)));
typedef unsigned short ushort8v __attribute__((ext_vector_type(8)));
typedef unsigned short ushort4v __attribute__((ext_vector_type(4)));
typedef __bf16         bf16x8   __attribute__((ext_vector_type(8)));

__device__ __forceinline__ unsigned short f2b(float x) {
  union { __bf16 b; unsigned short u; } v;
  v.b = (__bf16)x;                       // hw v_cvt (RNE) on gfx950
  return v.u;
}
__device__ __forceinline__ float b2f(unsigned short h) {
  union { unsigned u; float f; } v; v.u = ((unsigned)h) << 16;
  return v.f;
}

// async global->LDS, 16B per lane; LDS dest = wave-uniform base + lane*16
__device__ __forceinline__ void g2lds16(const unsigned short* g,
                                        unsigned short* l) {
  __builtin_amdgcn_global_load_lds(
      (const __attribute__((address_space(1))) unsigned int*)g,
      (__attribute__((address_space(3))) unsigned int*)l, 16, 0, 0);
}

// ---------- prep kernel: cvt + 6 weight transposes + rope cos table ------
__global__ __launch_bounds__(256) void prep_kernel(
    const float* __restrict__ X, unsigned short* __restrict__ Xb, int cvtb,
    int n8,
    const float* __restrict__ w0, unsigned short* __restrict__ t0,
    const float* __restrict__ w1, unsigned short* __restrict__ t1,
    const float* __restrict__ w2, unsigned short* __restrict__ t2,
    const float* __restrict__ w3, unsigned short* __restrict__ t3,
    const float* __restrict__ w4, unsigned short* __restrict__ t4,
    const float* __restrict__ w5, unsigned short* __restrict__ t5,
    const float* __restrict__ tq, const float* __restrict__ tk,
    f32x2* __restrict__ ctab) {
  __shared__ unsigned short T[64 * 72];
  const int tid = threadIdx.x;
  int blk = blockIdx.x;
  if (blk < cvtb) {
    int i = blk * 256 + tid;
    if (i >= n8) return;
    float8v v = reinterpret_cast<const float8v*>(X)[i];
    ushort8v h;
#pragma unroll
    for (int j = 0; j < 8; ++j) h[j] = f2b(v[j]);
    reinterpret_cast<ushort8v*>(Xb)[i] = h;
    return;
  }
  blk -= cvtb;
  if (blk >= 864) {
    // rope cos table
    int idx = (blk - 864) * 256 + tid;
    int row = idx >> 5, i = idx & 31;
    float f = exp2f(-(float)i * (13.287712379549449f / 32.f)); // 10000^(-i/32)
    f32x2 c;
    c[0] = cosf(tq[row] * f);
    c[1] = cosf(tk[row] * f);
    ctab[idx] = c;
    return;
  }
  const float* W; unsigned short* WT; int K, N, bx, by;
  if (blk < 256)      { W = w0; WT = t0; K = 1024; N = 1024; bx = blk & 15;         by = blk >> 4; }
  else if (blk < 512) { W = w1; WT = t1; K = 1024; N = 1024; bx = (blk - 256) & 15; by = (blk - 256) >> 4; }
  else if (blk < 544) { W = w2; WT = t2; K = 1024; N = 128;  bx = (blk - 512) & 1;  by = (blk - 512) >> 1; }
  else if (blk < 576) { W = w3; WT = t3; K = 128;  N = 1024; bx = (blk - 544) & 15; by = (blk - 544) >> 4; }
  else if (blk < 608) { W = w4; WT = t4; K = 128;  N = 1024; bx = (blk - 576) & 15; by = (blk - 576) >> 4; }
  else                { W = w5; WT = t5; K = 1024; N = 1024; bx = (blk - 608) & 15; by = (blk - 608) >> 4; }
  const int n0 = bx * 64, k0 = by * 64;
#pragma unroll
  for (int it = 0; it < 2; ++it) {
    int c = tid + it * 256;               // [0,512)
    int r = c >> 3, cc = c & 7;
    float8v v = *reinterpret_cast<const float8v*>(
        &W[(size_t)(k0 + r) * N + n0 + cc * 8]);
    ushort8v h;
#pragma unroll
    for (int j = 0; j < 8; ++j) h[j] = f2b(v[j]);
    *reinterpret_cast<ushort8v*>(&T[r * 72 + cc * 8]) = h;
  }
  __syncthreads();
#pragma unroll
  for (int it = 0; it < 2; ++it) {
    int c = tid + it * 256;
    int n = c >> 3, kc = c & 7;
    ushort8v y;
#pragma unroll
    for (int j = 0; j < 8; ++j) y[j] = T[(kc * 8 + j) * 72 + n];
    *reinterpret_cast<ushort8v*>(&WT[(size_t)(n0 + n) * K + k0 + kc * 8]) = y;
  }
}

// ------------ generic gemm_bt (single-buffer, XCD-swizzled 1D grid) -------
template <int TM, typename CT, bool ACC>
__global__ __launch_bounds__(256) void gemm_bt(
    const unsigned short* __restrict__ A, const unsigned short* __restrict__ Bt,
    CT* __restrict__ C, int M, int N, int K) {
  __shared__ unsigned short As[TM * 64];
  __shared__ unsigned short Bs[128 * 64];
  const int tid = threadIdx.x;
  const int id = blockIdx.x, cpx = gridDim.x >> 3;
  const int swz = (id & 7) * cpx + (id >> 3);
  const int nwx = N / 128;
  const int m0 = (swz / nwx) * TM, n0 = (swz % nwx) * 128;
  const int wave = tid >> 6, lane = tid & 63;
  const int wm = (wave >> 1) * (TM / 2), wn = (wave & 1) * 64;
  const int l16 = lane & 15, quad = lane >> 4;
  constexpr int MI = TM / 32;

  f32x4 acc[MI][4];
#pragma unroll
  for (int i = 0; i < MI; ++i)
#pragma unroll
    for (int j = 0; j < 4; ++j)
#pragma unroll
      for (int r = 0; r < 4; ++r) acc[i][j][r] = 0.f;

  for (int k0 = 0; k0 < K; k0 += 64) {
    __syncthreads();
#pragma unroll
    for (int it = 0; it < TM * 8 / 256; ++it) {
      int c = it * 256 + tid;
      int m = c >> 3, kc = (c & 7) ^ (m & 7);
      g2lds16(&A[(size_t)(m0 + m) * K + k0 + kc * 8], &As[c * 8]);
    }
#pragma unroll
    for (int it = 0; it < 4; ++it) {
      int c = it * 256 + tid;
      int n = c >> 3, kc = (c & 7) ^ (n & 7);
      g2lds16(&Bt[(size_t)(n0 + n) * K + k0 + kc * 8], &Bs[c * 8]);
    }
    __syncthreads();

#pragma unroll
    for (int ks = 0; ks < 2; ++ks) {
      bf16x8 af[MI], bfr[4];
#pragma unroll
      for (int mi = 0; mi < MI; ++mi) {
        int m = wm + mi * 16 + l16;
        af[mi] = *reinterpret_cast<const bf16x8*>(
            &As[(m * 8 + ((ks * 4 + quad) ^ (m & 7))) * 8]);
      }
#pragma unroll
      for (int ni = 0; ni < 4; ++ni) {
        int n = wn + ni * 16 + l16;
        bfr[ni] = *reinterpret_cast<const bf16x8*>(
            &Bs[(n * 8 + ((ks * 4 + quad) ^ (n & 7))) * 8]);
      }
#pragma unroll
      for (int mi = 0; mi < MI; ++mi)
#pragma unroll
        for (int ni = 0; ni < 4; ++ni)
          acc[mi][ni] = __builtin_amdgcn_mfma_f32_16x16x32_bf16(
              af[mi], bfr[ni], acc[mi][ni], 0, 0, 0);
    }
  }

#pragma unroll
  for (int mi = 0; mi < MI; ++mi)
#pragma unroll
    for (int ni = 0; ni < 4; ++ni) {
      int row = m0 + wm + mi * 16 + quad * 4;
      int col = n0 + wn + ni * 16 + l16;
#pragma unroll
      for (int r = 0; r < 4; ++r) {
        size_t idx = (size_t)(row + r) * N + col;
        float val = acc[mi][ni][r];
        if constexpr (sizeof(CT) == 2) {
          if constexpr (ACC) val += b2f(C[idx]);
          C[idx] = f2b(val);
        } else {
          if constexpr (ACC) val += C[idx];
          C[idx] = val;
        }
      }
    }
}

// -- fused GEMM #1 + rope: [q_r|k_r|c_kv] = X @ [wqr|wkr|wkvc]^T ----------
// Rope in epilogue via PRECOMPUTED cos table (R8 lesson: transcendentals in
// the epilogue spill acc to scratch). 1D grid (544 = 8*68) XCD-swizzled.
__global__ __launch_bounds__(256) void gemm_fused3(
    const unsigned short* __restrict__ A, const unsigned short* __restrict__ Bt,
    unsigned short* __restrict__ Cq, unsigned short* __restrict__ Ck,
    unsigned short* __restrict__ Cc, const f32x2* __restrict__ ctab, int K) {
  __shared__ unsigned short As[1024 * 8];
  __shared__ unsigned short Bs[1024 * 8];
  const int tid = threadIdx.x;
  const int id = blockIdx.x;
  const int swz = (id & 7) * 68 + (id >> 3);          // 544 = 8*68 bijective
  const int m0 = (swz / 17) * 128, n0 = (swz % 17) * 128;
  const int wave = tid >> 6, lane = tid & 63;
  const int wm = (wave >> 1) * 64, wn = (wave & 1) * 64;
  const int l16 = lane & 15, quad = lane >> 4;

  f32x4 acc[4][4];
#pragma unroll
  for (int i = 0; i < 4; ++i)
#pragma unroll
    for (int j = 0; j < 4; ++j)
#pragma unroll
      for (int r = 0; r < 4; ++r) acc[i][j][r] = 0.f;

  for (int k0 = 0; k0 < K; k0 += 64) {
    __syncthreads();
#pragma unroll
    for (int it = 0; it < 4; ++it) {
      int c = it * 256 + tid;
      int m = c >> 3, kc = (c & 7) ^ (m & 7);
      g2lds16(&A[(size_t)(m0 + m) * K + k0 + kc * 8], &As[c * 8]);
    }
#pragma unroll
    for (int it = 0; it < 4; ++it) {
      int c = it * 256 + tid;
      int n = c >> 3, kc = (c & 7) ^ (n & 7);
      g2lds16(&Bt[(size_t)(n0 + n) * K + k0 + kc * 8], &Bs[c * 8]);
    }
    __syncthreads();

#pragma unroll
    for (int ks = 0; ks < 2; ++ks) {
      bf16x8 af[4], bfr[4];
#pragma unroll
      for (int mi = 0; mi < 4; ++mi) {
        int m = wm + mi * 16 + l16;
        af[mi] = *reinterpret_cast<const bf16x8*>(
            &As[(m * 8 + ((ks * 4 + quad) ^ (m & 7))) * 8]);
      }
#pragma unroll
      for (int ni = 0; ni < 4; ++ni) {
        int n = wn + ni * 16 + l16;
        bfr[ni] = *reinterpret_cast<const bf16x8*>(
            &Bs[(n * 8 + ((ks * 4 + quad) ^ (n & 7))) * 8]);
      }
#pragma unroll
      for (int mi = 0; mi < 4; ++mi)
#pragma unroll
        for (int ni = 0; ni < 4; ++ni)
          acc[mi][ni] = __builtin_amdgcn_mfma_f32_16x16x32_bf16(
              af[mi], bfr[ni], acc[mi][ni], 0, 0, 0);
    }
  }

  if (n0 < 2048) {
    // rope path (q or k): cq/ck from table, pure FMA epilogue
    const bool isq = (n0 < 1024);
    unsigned short* dst = isq ? Cq : Ck;
    const int cb = isq ? 0 : 1024;
    const float s = isq ? 0.18033688011112042f : 1.0f;  // 0.125*log2(e) | 1
#pragma unroll
    for (int mi = 0; mi < 4; ++mi)
#pragma unroll
      for (int r = 0; r < 4; ++r) {
        int row = m0 + wm + mi * 16 + quad * 4 + r;
        const f32x2* crow = &ctab[(size_t)row * 32];
#pragma unroll
        for (int np = 0; np < 2; ++np) {
          f32x2 cc = crow[np * 16 + l16];        // {cq, ck}
          float v1 = acc[mi][np][r], v2 = acc[mi][np + 2][r];
          int col = n0 - cb + wn + np * 16 + l16;
          dst[(size_t)row * 1024 + col]      = f2b((v1 * cc[0] - v2 * cc[1]) * s);
          dst[(size_t)row * 1024 + col + 32] = f2b((v2 * cc[0] + v1 * cc[1]) * s);
        }
      }
  } else {
    // c_kv plain store
#pragma unroll
    for (int mi = 0; mi < 4; ++mi)
#pragma unroll
      for (int ni = 0; ni < 4; ++ni) {
        int row = m0 + wm + mi * 16 + quad * 4;
        int col = n0 - 2048 + wn + ni * 16 + l16;
#pragma unroll
        for (int r = 0; r < 4; ++r)
          Cc[(size_t)(row + r) * 128 + col] = f2b(acc[mi][ni][r]);
      }
  }
}

// ------- fused GEMM #2: [k_c(acc->ksb) | v_c -> Vt direct] ---------------
// k_c accumulates onto rope'd k_r; v_c stored directly into sigma^-1-
// permuted Vt[b,h,d,l'] (8B stores, eliminates vtrans).
__global__ __launch_bounds__(256) void gemm_fused2(
    const unsigned short* __restrict__ A, const unsigned short* __restrict__ Bt,
    unsigned short* __restrict__ Ck, unsigned short* __restrict__ vt, int K) {
  __shared__ unsigned short As[1024 * 8];
  __shared__ unsigned short Bs[1024 * 8];
  const int tid = threadIdx.x;
  const int m0 = blockIdx.y * 128, n0 = blockIdx.x * 128;
  const int wave = tid >> 6, lane = tid & 63;
  const int wm = (wave >> 1) * 64, wn = (wave & 1) * 64;
  const int l16 = lane & 15, quad = lane >> 4;

  f32x4 acc[4][4];
#pragma unroll
  for (int i = 0; i < 4; ++i)
#pragma unroll
    for (int j = 0; j < 4; ++j)
#pragma unroll
      for (int r = 0; r < 4; ++r) acc[i][j][r] = 0.f;

  for (int k0 = 0; k0 < K; k0 += 64) {
    __syncthreads();
#pragma unroll
    for (int it = 0; it < 4; ++it) {
      int c = it * 256 + tid;
      int m = c >> 3, kc = (c & 7) ^ (m & 7);
      g2lds16(&A[(size_t)(m0 + m) * K + k0 + kc * 8], &As[c * 8]);
    }
#pragma unroll
    for (int it = 0; it < 4; ++it) {
      int c = it * 256 + tid;
      int n = c >> 3, kc = (c & 7) ^ (n & 7);
      g2lds16(&Bt[(size_t)(n0 + n) * K + k0 + kc * 8], &Bs[c * 8]);
    }
    __syncthreads();

#pragma unroll
    for (int ks = 0; ks < 2; ++ks) {
      bf16x8 af[4], bfr[4];
#pragma unroll
      for (int mi = 0; mi < 4; ++mi) {
        int m = wm + mi * 16 + l16;
        af[mi] = *reinterpret_cast<const bf16x8*>(
            &As[(m * 8 + ((ks * 4 + quad) ^ (m & 7))) * 8]);
      }
#pragma unroll
      for (int ni = 0; ni < 4; ++ni) {
        int n = wn + ni * 16 + l16;
        bfr[ni] = *reinterpret_cast<const bf16x8*>(
            &Bs[(n * 8 + ((ks * 4 + quad) ^ (n & 7))) * 8]);
      }
#pragma unroll
      for (int mi = 0; mi < 4; ++mi)
#pragma unroll
        for (int ni = 0; ni < 4; ++ni)
          acc[mi][ni] = __builtin_amdgcn_mfma_f32_16x16x32_bf16(
              af[mi], bfr[ni], acc[mi][ni], 0, 0, 0);
    }
  }

  if (n0 < 1024) {
    // k_c: accumulate onto rope'd k_r
#pragma unroll
    for (int mi = 0; mi < 4; ++mi)
#pragma unroll
      for (int ni = 0; ni < 4; ++ni) {
        int row = m0 + wm + mi * 16 + quad * 4;
        int col = n0 + wn + ni * 16 + l16;
#pragma unroll
        for (int r = 0; r < 4; ++r) {
          size_t idx = (size_t)(row + r) * 1024 + col;
          Ck[idx] = f2b(acc[mi][ni][r] + b2f(Ck[idx]));
        }
      }
  } else {
    // v_c -> Vt[b,h,d,sigma^-1(l)] direct, 8B stores
    const int L = 2048;
#pragma unroll
    for (int mi = 0; mi < 4; ++mi)
#pragma unroll
      for (int ni = 0; ni < 4; ++ni) {
        int row = m0 + wm + mi * 16 + quad * 4;       // row % 4 == 0
        int col = n0 - 1024 + wn + ni * 16 + l16;     // h*64 + d
        int l = row & (L - 1);
        int bh = ((row >> 11) << 4) | (col >> 6);
        int d = col & 63;
        int s = (l & ~63) | (((l >> 5) & 1) << 5) | (((l >> 3) & 1) << 4) |
                (((l >> 2) & 1) << 3) | (((l >> 4) & 1) << 2);
        ushort4v w;
#pragma unroll
        for (int r = 0; r < 4; ++r) w[r] = f2b(acc[mi][ni][r]);
        *reinterpret_cast<ushort4v*>(
            &vt[(size_t)bh * 64 * L + (size_t)d * L + s]) = w;
      }
  }
}

// ---------- flash v17: 4 waves x 32q + 3-buffer counted-vmcnt (T4) --------
// flash14 compute (2 m-tiles/wave, K/V frags read once, register-sigma P)
// with a 3-deep staging pipeline: raw s_barriers + counted vmcnt instead of
// __syncthreads' vmcnt(0) drain. Per step:
//   barrier A  (compute(t-1) done everywhere -> buf (t+2)%3 == (t-1)%3 free)
//   issue stage(t+2)                                  [4 loads/thread]
//   s_waitcnt vmcnt(8|4|0)  (in-order: tile t's loads complete)
//   barrier B  (tile t visible to all waves) -> compute(t)
// LDS 48KB (3x(K8K+V8K)) -> 3 blocks/CU -> 12 waves/CU; loads for t+1,t+2
// stay in flight across barriers.
__global__ __launch_bounds__(256, 3) void flash17_kernel(
    const unsigned short* __restrict__ qs, const unsigned short* __restrict__ ks,
    const unsigned short* __restrict__ vt, unsigned short* __restrict__ o,
    int L) {
  __shared__ unsigned short Ks[3][512 * 8];   // 64 key x 64 d, swizzled
  __shared__ unsigned short Vs[3][512 * 8];   // 64 d x 64 key(perm), swizzled
  const int tid = threadIdx.x;
  const int wave = tid >> 6, lane = tid & 63;
  const int l16 = lane & 15, quad = lane >> 4;
  const int bh = blockIdx.y;                   // b*16 + h
  const int qb = blockIdx.x * 128 + wave * 32; // this wave's 32 q rows
  const size_t base = ((size_t)(bh >> 4) * L) * 1024 + (bh & 15) * 64;
  const size_t vtbase = (size_t)bh * 64 * L;

  bf16x8 aq[2][2];
#pragma unroll
  for (int mt = 0; mt < 2; ++mt) {
    size_t qrow = base + (size_t)(qb + mt * 16 + l16) * 1024;
    aq[mt][0] = *reinterpret_cast<const bf16x8*>(&qs[qrow + quad * 8]);
    aq[mt][1] = *reinterpret_cast<const bf16x8*>(&qs[qrow + 32 + quad * 8]);
  }

  ushort8v onesu;
#pragma unroll
  for (int j = 0; j < 8; ++j) onesu[j] = 0x3F80;  // bf16 1.0
  bf16x8 ones = *reinterpret_cast<bf16x8*>(&onesu);

  f32x4 oacc[2][4];
  f32x4 lacc[2];
#pragma unroll
  for (int mt = 0; mt < 2; ++mt) {
#pragma unroll
    for (int r = 0; r < 4; ++r) lacc[mt][r] = 0.f;
#pragma unroll
    for (int nt = 0; nt < 4; ++nt)
#pragma unroll
      for (int r = 0; r < 4; ++r) oacc[mt][nt][r] = 0.f;
  }

  auto stage = [&](int t, int b) {
    int k0 = t * 64;
#pragma unroll
    for (int it = 0; it < 2; ++it) {
      int c = it * 256 + tid;                  // [0,512)
      int key = c >> 3, dc = (c & 7) ^ (key & 7);
      g2lds16(&ks[base + (size_t)(k0 + key) * 1024 + dc * 8], &Ks[b][c * 8]);
    }
#pragma unroll
    for (int it = 0; it < 2; ++it) {
      int c = it * 256 + tid;
      int d = c >> 3, kc = (c & 7) ^ (d & 7);
      g2lds16(&vt[vtbase + (size_t)d * L + k0 + kc * 8], &Vs[b][c * 8]);
    }
  };

  const int T = L / 64;
  stage(0, 0);
  stage(1, 1);

  for (int t = 0; t < T; ++t) {
    __builtin_amdgcn_s_barrier();            // A: compute(t-1) done everywhere
    asm volatile("" ::: "memory");
    if (t + 2 < T) stage(t + 2, (t + 2) % 3);
    if (t + 2 < T)
      asm volatile("s_waitcnt vmcnt(8)" ::: "memory");
    else if (t + 1 < T)
      asm volatile("s_waitcnt vmcnt(4)" ::: "memory");
    else
      asm volatile("s_waitcnt vmcnt(0)" ::: "memory");
    __builtin_amdgcn_s_barrier();            // B: tile t visible to all
    asm volatile("" ::: "memory");

    const int cb = t % 3;
    const unsigned short* Kb = &Ks[cb][0];
    const unsigned short* Vb = &Vs[cb][0];

    // S^T = K Q^T for BOTH m-tiles; K fragments read once.
    f32x4 st[2][4];
#pragma unroll
    for (int nt = 0; nt < 4; ++nt) {
      int key = nt * 16 + l16;
      int dc0 = quad ^ (key & 7);
      int dc1 = (4 + quad) ^ (key & 7);
      bf16x8 bk0 = *reinterpret_cast<const bf16x8*>(&Kb[(key * 8 + dc0) * 8]);
      bf16x8 bk1 = *reinterpret_cast<const bf16x8*>(&Kb[(key * 8 + dc1) * 8]);
#pragma unroll
      for (int mt = 0; mt < 2; ++mt) {
        f32x4 z; z[0] = z[1] = z[2] = z[3] = 0.f;
        z = __builtin_amdgcn_mfma_f32_16x16x32_bf16(bk0, aq[mt][0], z, 0, 0, 0);
        z = __builtin_amdgcn_mfma_f32_16x16x32_bf16(bk1, aq[mt][1], z, 0, 0, 0);
        st[mt][nt] = z;
      }
    }

    // exp2 -> ap frags by pure register renaming (key-permutation sigma)
    bf16x8 ap[2][2];
#pragma unroll
    for (int mt = 0; mt < 2; ++mt) {
#pragma unroll
      for (int hf = 0; hf < 2; ++hf)
#pragma unroll
        for (int w = 0; w < 4; ++w) {
          int nt = 2 * hf + (w >> 1), p = w & 1;
          ap[mt][hf][2 * w] =
              (__bf16)__builtin_amdgcn_exp2f(st[mt][nt][2 * p]);
          ap[mt][hf][2 * w + 1] =
              (__bf16)__builtin_amdgcn_exp2f(st[mt][nt][2 * p + 1]);
        }
      lacc[mt] = __builtin_amdgcn_mfma_f32_16x16x32_bf16(ap[mt][0], ones,
                                                         lacc[mt], 0, 0, 0);
      lacc[mt] = __builtin_amdgcn_mfma_f32_16x16x32_bf16(ap[mt][1], ones,
                                                         lacc[mt], 0, 0, 0);
    }

    // O += P V (V fragments read once, reused by both m-tiles)
#pragma unroll
    for (int nt = 0; nt < 4; ++nt) {
      int d = nt * 16 + l16;
#pragma unroll
      for (int hf = 0; hf < 2; ++hf) {
        int kc = (hf * 4 + quad) ^ (d & 7);
        bf16x8 bv = *reinterpret_cast<const bf16x8*>(&Vb[(d * 8 + kc) * 8]);
#pragma unroll
        for (int mt = 0; mt < 2; ++mt)
          oacc[mt][nt] = __builtin_amdgcn_mfma_f32_16x16x32_bf16(
              ap[mt][hf], bv, oacc[mt][nt], 0, 0, 0);
      }
    }
  }

#pragma unroll
  for (int mt = 0; mt < 2; ++mt)
#pragma unroll
    for (int r = 0; r < 4; ++r) {
      float inv = __builtin_amdgcn_rcpf(lacc[mt][r]);
      int q = qb + mt * 16 + quad * 4 + r;
#pragma unroll
      for (int nt = 0; nt < 4; ++nt)
        o[base + (size_t)q * 1024 + nt * 16 + l16] =
            f2b(oacc[mt][nt][r] * inv);
    }
}

// ---------------- driver ----------------
extern "C" void kernel_launch(void* const* d_in, const int* in_sizes, int n_in,
                              void* d_out, int out_size, void* d_ws, size_t ws_size,
                              hipStream_t stream) {
  const float* X    = (const float*)d_in[0];
  const float* tq   = (const float*)d_in[1];
  const float* tk   = (const float*)d_in[2];
  const float* wkvc = (const float*)d_in[3];
  const float* wkc  = (const float*)d_in[4];
  const float* wvc  = (const float*)d_in[5];
  const float* wqr  = (const float*)d_in[6];
  const float* wkr  = (const float*)d_in[7];
  const float* wo   = (const float*)d_in[8];

  const int D = 1024, DC = 128, L = 2048;
  const int M = in_sizes[0] / D;       // B*L
  const int B = M / L;
  const int NBH = B * 16;
  (void)n_in; (void)out_size; (void)ws_size;

  unsigned short* p = (unsigned short*)d_ws;
  auto take = [&](size_t n) { unsigned short* r = p; p += n; return r; };
  unsigned short* Xb    = take((size_t)M * D);
  unsigned short* qsb   = take((size_t)M * D);
  unsigned short* ksb   = take((size_t)M * D);
  unsigned short* vcb   = take((size_t)M * D);
  unsigned short* ckv   = take((size_t)M * DC);
  unsigned short* Wbig  = take((size_t)(2 * D + DC) * D);   // [wqr|wkr|wkvc]^T
  unsigned short* Wkcvc = take((size_t)(2 * D) * DC);       // [wkc|wvc]^T
  unsigned short* WoT   = take((size_t)D * D);
  f32x2* ctab = (f32x2*)take((size_t)M * 32 * 4);           // M*32 float2
  unsigned short* vtb   = Xb;   // Xb dead after fused3 gemm; fused2 writes Vt
  unsigned short* obuf  = vcb;  // flash O lands here

  // prep: cvt + all 6 weight transposes + rope cos table in ONE launch
  const int n8 = M * D / 8;
  const int cvtb = (n8 + 255) / 256;
  const int ropeb = M / 8;             // M*32 threads / 256
  prep_kernel<<<cvtb + 864 + ropeb, 256, 0, stream>>>(
      X, Xb, cvtb, n8,
      wqr,  Wbig,
      wkr,  Wbig + (size_t)D * D,
      wkvc, Wbig + (size_t)2 * D * D,
      wkc,  Wkcvc,
      wvc,  Wkcvc + (size_t)D * DC,
      wo,   WoT,
      tq, tk, ctab);

  {
    // 1D grid 17*32 = 544 = 8*68, XCD-chunk-swizzled in-kernel
    gemm_fused3<<<(2 * D + DC) / 128 * (M / 128), 256, 0, stream>>>(
        Xb, Wbig, qsb, ksb, ckv, ctab, D);
  }
  {
    dim3 g(2 * D / 128, M / 128);                          // (16, 32)
    gemm_fused2<<<g, 256, 0, stream>>>(ckv, Wkcvc, ksb, vtb, DC);
  }

  dim3 fg(L / 128, NBH);                                   // (16, 32)
  flash17_kernel<<<fg, 256, 0, stream>>>(qsb, ksb, vtb, obuf, L);

  {
    // 1D grid (D/128)*(M/128) = 8*32 = 256 = 1 block/CU, swizzled
    gemm_bt<128, float, false><<<(D / 128) * (M / 128), 256, 0, stream>>>(
        obuf, WoT, (float*)d_out, M, D, D);
  }
}

// Round 12
// 199.264 us; speedup vs baseline: 1.0215x; 1.0215x over previous
//
#include <hip/hip_runtime.h>

typedef float          f32x4    __attribute__((ext_vector_type(4)));
typedef float          f32x2    __attribute__((ext_vector_type(2)));
typedef float          float8v  __attribute__((ext_vector_type(8)));
typedef unsigned short ushort8v __attribute__((ext_vector_type(8)));
typedef unsigned short ushort4v __attribute__((ext_vector_type(4)));
typedef __bf16         bf16x8   __attribute__((ext_vector_type(8)));

__device__ __forceinline__ unsigned short f2b(float x) {
  union { __bf16 b; unsigned short u; } v;
  v.b = (__bf16)x;                       // hw v_cvt (RNE) on gfx950
  return v.u;
}
__device__ __forceinline__ float b2f(unsigned short h) {
  union { unsigned u; float f; } v; v.u = ((unsigned)h) << 16;
  return v.f;
}

// async global->LDS, 16B per lane; LDS dest = wave-uniform base + lane*16
__device__ __forceinline__ void g2lds16(const unsigned short* g,
                                        unsigned short* l) {
  __builtin_amdgcn_global_load_lds(
      (const __attribute__((address_space(1))) unsigned int*)g,
      (__attribute__((address_space(3))) unsigned int*)l, 16, 0, 0);
}

// ---------- prep kernel: cvt + 6 weight transposes + rope cos table ------
__global__ __launch_bounds__(256) void prep_kernel(
    const float* __restrict__ X, unsigned short* __restrict__ Xb, int cvtb,
    int n8,
    const float* __restrict__ w0, unsigned short* __restrict__ t0,
    const float* __restrict__ w1, unsigned short* __restrict__ t1,
    const float* __restrict__ w2, unsigned short* __restrict__ t2,
    const float* __restrict__ w3, unsigned short* __restrict__ t3,
    const float* __restrict__ w4, unsigned short* __restrict__ t4,
    const float* __restrict__ w5, unsigned short* __restrict__ t5,
    const float* __restrict__ tq, const float* __restrict__ tk,
    f32x2* __restrict__ ctab) {
  __shared__ unsigned short T[64 * 72];
  const int tid = threadIdx.x;
  int blk = blockIdx.x;
  if (blk < cvtb) {
    int i = blk * 256 + tid;
    if (i >= n8) return;
    float8v v = reinterpret_cast<const float8v*>(X)[i];
    ushort8v h;
#pragma unroll
    for (int j = 0; j < 8; ++j) h[j] = f2b(v[j]);
    reinterpret_cast<ushort8v*>(Xb)[i] = h;
    return;
  }
  blk -= cvtb;
  if (blk >= 864) {
    // rope cos table
    int idx = (blk - 864) * 256 + tid;
    int row = idx >> 5, i = idx & 31;
    float f = exp2f(-(float)i * (13.287712379549449f / 32.f)); // 10000^(-i/32)
    f32x2 c;
    c[0] = cosf(tq[row] * f);
    c[1] = cosf(tk[row] * f);
    ctab[idx] = c;
    return;
  }
  const float* W; unsigned short* WT; int K, N, bx, by;
  if (blk < 256)      { W = w0; WT = t0; K = 1024; N = 1024; bx = blk & 15;         by = blk >> 4; }
  else if (blk < 512) { W = w1; WT = t1; K = 1024; N = 1024; bx = (blk - 256) & 15; by = (blk - 256) >> 4; }
  else if (blk < 544) { W = w2; WT = t2; K = 1024; N = 128;  bx = (blk - 512) & 1;  by = (blk - 512) >> 1; }
  else if (blk < 576) { W = w3; WT = t3; K = 128;  N = 1024; bx = (blk - 544) & 15; by = (blk - 544) >> 4; }
  else if (blk < 608) { W = w4; WT = t4; K = 128;  N = 1024; bx = (blk - 576) & 15; by = (blk - 576) >> 4; }
  else                { W = w5; WT = t5; K = 1024; N = 1024; bx = (blk - 608) & 15; by = (blk - 608) >> 4; }
  const int n0 = bx * 64, k0 = by * 64;
#pragma unroll
  for (int it = 0; it < 2; ++it) {
    int c = tid + it * 256;               // [0,512)
    int r = c >> 3, cc = c & 7;
    float8v v = *reinterpret_cast<const float8v*>(
        &W[(size_t)(k0 + r) * N + n0 + cc * 8]);
    ushort8v h;
#pragma unroll
    for (int j = 0; j < 8; ++j) h[j] = f2b(v[j]);
    *reinterpret_cast<ushort8v*>(&T[r * 72 + cc * 8]) = h;
  }
  __syncthreads();
#pragma unroll
  for (int it = 0; it < 2; ++it) {
    int c = tid + it * 256;
    int n = c >> 3, kc = c & 7;
    ushort8v y;
#pragma unroll
    for (int j = 0; j < 8; ++j) y[j] = T[(kc * 8 + j) * 72 + n];
    *reinterpret_cast<ushort8v*>(&WT[(size_t)(n0 + n) * K + k0 + kc * 8]) = y;
  }
}

// ------------ generic gemm_bt (single-buffer, XCD-swizzled 1D grid) -------
template <int TM, typename CT, bool ACC>
__global__ __launch_bounds__(256) void gemm_bt(
    const unsigned short* __restrict__ A, const unsigned short* __restrict__ Bt,
    CT* __restrict__ C, int M, int N, int K) {
  __shared__ unsigned short As[TM * 64];
  __shared__ unsigned short Bs[128 * 64];
  const int tid = threadIdx.x;
  const int id = blockIdx.x, cpx = gridDim.x >> 3;
  const int swz = (id & 7) * cpx + (id >> 3);
  const int nwx = N / 128;
  const int m0 = (swz / nwx) * TM, n0 = (swz % nwx) * 128;
  const int wave = tid >> 6, lane = tid & 63;
  const int wm = (wave >> 1) * (TM / 2), wn = (wave & 1) * 64;
  const int l16 = lane & 15, quad = lane >> 4;
  constexpr int MI = TM / 32;

  f32x4 acc[MI][4];
#pragma unroll
  for (int i = 0; i < MI; ++i)
#pragma unroll
    for (int j = 0; j < 4; ++j)
#pragma unroll
      for (int r = 0; r < 4; ++r) acc[i][j][r] = 0.f;

  for (int k0 = 0; k0 < K; k0 += 64) {
    __syncthreads();
#pragma unroll
    for (int it = 0; it < TM * 8 / 256; ++it) {
      int c = it * 256 + tid;
      int m = c >> 3, kc = (c & 7) ^ (m & 7);
      g2lds16(&A[(size_t)(m0 + m) * K + k0 + kc * 8], &As[c * 8]);
    }
#pragma unroll
    for (int it = 0; it < 4; ++it) {
      int c = it * 256 + tid;
      int n = c >> 3, kc = (c & 7) ^ (n & 7);
      g2lds16(&Bt[(size_t)(n0 + n) * K + k0 + kc * 8], &Bs[c * 8]);
    }
    __syncthreads();

#pragma unroll
    for (int ks = 0; ks < 2; ++ks) {
      bf16x8 af[MI], bfr[4];
#pragma unroll
      for (int mi = 0; mi < MI; ++mi) {
        int m = wm + mi * 16 + l16;
        af[mi] = *reinterpret_cast<const bf16x8*>(
            &As[(m * 8 + ((ks * 4 + quad) ^ (m & 7))) * 8]);
      }
#pragma unroll
      for (int ni = 0; ni < 4; ++ni) {
        int n = wn + ni * 16 + l16;
        bfr[ni] = *reinterpret_cast<const bf16x8*>(
            &Bs[(n * 8 + ((ks * 4 + quad) ^ (n & 7))) * 8]);
      }
#pragma unroll
      for (int mi = 0; mi < MI; ++mi)
#pragma unroll
        for (int ni = 0; ni < 4; ++ni)
          acc[mi][ni] = __builtin_amdgcn_mfma_f32_16x16x32_bf16(
              af[mi], bfr[ni], acc[mi][ni], 0, 0, 0);
    }
  }

#pragma unroll
  for (int mi = 0; mi < MI; ++mi)
#pragma unroll
    for (int ni = 0; ni < 4; ++ni) {
      int row = m0 + wm + mi * 16 + quad * 4;
      int col = n0 + wn + ni * 16 + l16;
#pragma unroll
      for (int r = 0; r < 4; ++r) {
        size_t idx = (size_t)(row + r) * N + col;
        float val = acc[mi][ni][r];
        if constexpr (sizeof(CT) == 2) {
          if constexpr (ACC) val += b2f(C[idx]);
          C[idx] = f2b(val);
        } else {
          if constexpr (ACC) val += C[idx];
          C[idx] = val;
        }
      }
    }
}

// -- fused GEMM #1 + rope: [q_r|k_r|c_kv] = X @ [wqr|wkr|wkvc]^T ----------
// Rope in epilogue via PRECOMPUTED cos table (R8 lesson: transcendentals in
// the epilogue spill acc to scratch). 1D grid (544 = 8*68) XCD-swizzled.
__global__ __launch_bounds__(256) void gemm_fused3(
    const unsigned short* __restrict__ A, const unsigned short* __restrict__ Bt,
    unsigned short* __restrict__ Cq, unsigned short* __restrict__ Ck,
    unsigned short* __restrict__ Cc, const f32x2* __restrict__ ctab, int K) {
  __shared__ unsigned short As[1024 * 8];
  __shared__ unsigned short Bs[1024 * 8];
  const int tid = threadIdx.x;
  const int id = blockIdx.x;
  const int swz = (id & 7) * 68 + (id >> 3);          // 544 = 8*68 bijective
  const int m0 = (swz / 17) * 128, n0 = (swz % 17) * 128;
  const int wave = tid >> 6, lane = tid & 63;
  const int wm = (wave >> 1) * 64, wn = (wave & 1) * 64;
  const int l16 = lane & 15, quad = lane >> 4;

  f32x4 acc[4][4];
#pragma unroll
  for (int i = 0; i < 4; ++i)
#pragma unroll
    for (int j = 0; j < 4; ++j)
#pragma unroll
      for (int r = 0; r < 4; ++r) acc[i][j][r] = 0.f;

  for (int k0 = 0; k0 < K; k0 += 64) {
    __syncthreads();
#pragma unroll
    for (int it = 0; it < 4; ++it) {
      int c = it * 256 + tid;
      int m = c >> 3, kc = (c & 7) ^ (m & 7);
      g2lds16(&A[(size_t)(m0 + m) * K + k0 + kc * 8], &As[c * 8]);
    }
#pragma unroll
    for (int it = 0; it < 4; ++it) {
      int c = it * 256 + tid;
      int n = c >> 3, kc = (c & 7) ^ (n & 7);
      g2lds16(&Bt[(size_t)(n0 + n) * K + k0 + kc * 8], &Bs[c * 8]);
    }
    __syncthreads();

#pragma unroll
    for (int ks = 0; ks < 2; ++ks) {
      bf16x8 af[4], bfr[4];
#pragma unroll
      for (int mi = 0; mi < 4; ++mi) {
        int m = wm + mi * 16 + l16;
        af[mi] = *reinterpret_cast<const bf16x8*>(
            &As[(m * 8 + ((ks * 4 + quad) ^ (m & 7))) * 8]);
      }
#pragma unroll
      for (int ni = 0; ni < 4; ++ni) {
        int n = wn + ni * 16 + l16;
        bfr[ni] = *reinterpret_cast<const bf16x8*>(
            &Bs[(n * 8 + ((ks * 4 + quad) ^ (n & 7))) * 8]);
      }
#pragma unroll
      for (int mi = 0; mi < 4; ++mi)
#pragma unroll
        for (int ni = 0; ni < 4; ++ni)
          acc[mi][ni] = __builtin_amdgcn_mfma_f32_16x16x32_bf16(
              af[mi], bfr[ni], acc[mi][ni], 0, 0, 0);
    }
  }

  if (n0 < 2048) {
    // rope path (q or k): cq/ck from table, pure FMA epilogue
    const bool isq = (n0 < 1024);
    unsigned short* dst = isq ? Cq : Ck;
    const int cb = isq ? 0 : 1024;
    const float s = isq ? 0.18033688011112042f : 1.0f;  // 0.125*log2(e) | 1
#pragma unroll
    for (int mi = 0; mi < 4; ++mi)
#pragma unroll
      for (int r = 0; r < 4; ++r) {
        int row = m0 + wm + mi * 16 + quad * 4 + r;
        const f32x2* crow = &ctab[(size_t)row * 32];
#pragma unroll
        for (int np = 0; np < 2; ++np) {
          f32x2 cc = crow[np * 16 + l16];        // {cq, ck}
          float v1 = acc[mi][np][r], v2 = acc[mi][np + 2][r];
          int col = n0 - cb + wn + np * 16 + l16;
          dst[(size_t)row * 1024 + col]      = f2b((v1 * cc[0] - v2 * cc[1]) * s);
          dst[(size_t)row * 1024 + col + 32] = f2b((v2 * cc[0] + v1 * cc[1]) * s);
        }
      }
  } else {
    // c_kv plain store
#pragma unroll
    for (int mi = 0; mi < 4; ++mi)
#pragma unroll
      for (int ni = 0; ni < 4; ++ni) {
        int row = m0 + wm + mi * 16 + quad * 4;
        int col = n0 - 2048 + wn + ni * 16 + l16;
#pragma unroll
        for (int r = 0; r < 4; ++r)
          Cc[(size_t)(row + r) * 128 + col] = f2b(acc[mi][ni][r]);
      }
  }
}

// ------- fused GEMM #2: [k_c(acc->ksb) | v_c -> Vt direct] ---------------
// k_c accumulates onto rope'd k_r; v_c stored directly into sigma^-1-
// permuted Vt[b,h,d,l'] (8B stores, eliminates vtrans). 1D grid 512 = 8*64
// XCD-swizzled.
__global__ __launch_bounds__(256) void gemm_fused2(
    const unsigned short* __restrict__ A, const unsigned short* __restrict__ Bt,
    unsigned short* __restrict__ Ck, unsigned short* __restrict__ vt, int K) {
  __shared__ unsigned short As[1024 * 8];
  __shared__ unsigned short Bs[1024 * 8];
  const int tid = threadIdx.x;
  const int id = blockIdx.x;
  const int swz = (id & 7) * 64 + (id >> 3);          // 512 = 8*64 bijective
  const int m0 = (swz >> 4) * 128, n0 = (swz & 15) * 128;
  const int wave = tid >> 6, lane = tid & 63;
  const int wm = (wave >> 1) * 64, wn = (wave & 1) * 64;
  const int l16 = lane & 15, quad = lane >> 4;

  f32x4 acc[4][4];
#pragma unroll
  for (int i = 0; i < 4; ++i)
#pragma unroll
    for (int j = 0; j < 4; ++j)
#pragma unroll
      for (int r = 0; r < 4; ++r) acc[i][j][r] = 0.f;

  for (int k0 = 0; k0 < K; k0 += 64) {
    __syncthreads();
#pragma unroll
    for (int it = 0; it < 4; ++it) {
      int c = it * 256 + tid;
      int m = c >> 3, kc = (c & 7) ^ (m & 7);
      g2lds16(&A[(size_t)(m0 + m) * K + k0 + kc * 8], &As[c * 8]);
    }
#pragma unroll
    for (int it = 0; it < 4; ++it) {
      int c = it * 256 + tid;
      int n = c >> 3, kc = (c & 7) ^ (n & 7);
      g2lds16(&Bt[(size_t)(n0 + n) * K + k0 + kc * 8], &Bs[c * 8]);
    }
    __syncthreads();

#pragma unroll
    for (int ks = 0; ks < 2; ++ks) {
      bf16x8 af[4], bfr[4];
#pragma unroll
      for (int mi = 0; mi < 4; ++mi) {
        int m = wm + mi * 16 + l16;
        af[mi] = *reinterpret_cast<const bf16x8*>(
            &As[(m * 8 + ((ks * 4 + quad) ^ (m & 7))) * 8]);
      }
#pragma unroll
      for (int ni = 0; ni < 4; ++ni) {
        int n = wn + ni * 16 + l16;
        bfr[ni] = *reinterpret_cast<const bf16x8*>(
            &Bs[(n * 8 + ((ks * 4 + quad) ^ (n & 7))) * 8]);
      }
#pragma unroll
      for (int mi = 0; mi < 4; ++mi)
#pragma unroll
        for (int ni = 0; ni < 4; ++ni)
          acc[mi][ni] = __builtin_amdgcn_mfma_f32_16x16x32_bf16(
              af[mi], bfr[ni], acc[mi][ni], 0, 0, 0);
    }
  }

  if (n0 < 1024) {
    // k_c: accumulate onto rope'd k_r
#pragma unroll
    for (int mi = 0; mi < 4; ++mi)
#pragma unroll
      for (int ni = 0; ni < 4; ++ni) {
        int row = m0 + wm + mi * 16 + quad * 4;
        int col = n0 + wn + ni * 16 + l16;
#pragma unroll
        for (int r = 0; r < 4; ++r) {
          size_t idx = (size_t)(row + r) * 1024 + col;
          Ck[idx] = f2b(acc[mi][ni][r] + b2f(Ck[idx]));
        }
      }
  } else {
    // v_c -> Vt[b,h,d,sigma^-1(l)] direct, 8B stores
    const int L = 2048;
#pragma unroll
    for (int mi = 0; mi < 4; ++mi)
#pragma unroll
      for (int ni = 0; ni < 4; ++ni) {
        int row = m0 + wm + mi * 16 + quad * 4;       // row % 4 == 0
        int col = n0 - 1024 + wn + ni * 16 + l16;     // h*64 + d
        int l = row & (L - 1);
        int bh = ((row >> 11) << 4) | (col >> 6);
        int d = col & 63;
        int s = (l & ~63) | (((l >> 5) & 1) << 5) | (((l >> 3) & 1) << 4) |
                (((l >> 2) & 1) << 3) | (((l >> 4) & 1) << 2);
        ushort4v w;
#pragma unroll
        for (int r = 0; r < 4; ++r) w[r] = f2b(acc[mi][ni][r]);
        *reinterpret_cast<ushort4v*>(
            &vt[(size_t)bh * 64 * L + (size_t)d * L + s]) = w;
      }
  }
}

// ---------- flash v17: 4 waves x 32q + 3-buffer counted-vmcnt (T4) --------
// flash14 compute (2 m-tiles/wave, K/V frags read once, register-sigma P)
// with a 3-deep staging pipeline: raw s_barriers + counted vmcnt instead of
// __syncthreads' vmcnt(0) drain. 48KB LDS -> 3 blocks/CU -> 12 waves/CU.
__global__ __launch_bounds__(256, 3) void flash17_kernel(
    const unsigned short* __restrict__ qs, const unsigned short* __restrict__ ks,
    const unsigned short* __restrict__ vt, unsigned short* __restrict__ o,
    int L) {
  __shared__ unsigned short Ks[3][512 * 8];   // 64 key x 64 d, swizzled
  __shared__ unsigned short Vs[3][512 * 8];   // 64 d x 64 key(perm), swizzled
  const int tid = threadIdx.x;
  const int wave = tid >> 6, lane = tid & 63;
  const int l16 = lane & 15, quad = lane >> 4;
  const int bh = blockIdx.y;                   // b*16 + h
  const int qb = blockIdx.x * 128 + wave * 32; // this wave's 32 q rows
  const size_t base = ((size_t)(bh >> 4) * L) * 1024 + (bh & 15) * 64;
  const size_t vtbase = (size_t)bh * 64 * L;

  bf16x8 aq[2][2];
#pragma unroll
  for (int mt = 0; mt < 2; ++mt) {
    size_t qrow = base + (size_t)(qb + mt * 16 + l16) * 1024;
    aq[mt][0] = *reinterpret_cast<const bf16x8*>(&qs[qrow + quad * 8]);
    aq[mt][1] = *reinterpret_cast<const bf16x8*>(&qs[qrow + 32 + quad * 8]);
  }

  ushort8v onesu;
#pragma unroll
  for (int j = 0; j < 8; ++j) onesu[j] = 0x3F80;  // bf16 1.0
  bf16x8 ones = *reinterpret_cast<bf16x8*>(&onesu);

  f32x4 oacc[2][4];
  f32x4 lacc[2];
#pragma unroll
  for (int mt = 0; mt < 2; ++mt) {
#pragma unroll
    for (int r = 0; r < 4; ++r) lacc[mt][r] = 0.f;
#pragma unroll
    for (int nt = 0; nt < 4; ++nt)
#pragma unroll
      for (int r = 0; r < 4; ++r) oacc[mt][nt][r] = 0.f;
  }

  auto stage = [&](int t, int b) {
    int k0 = t * 64;
#pragma unroll
    for (int it = 0; it < 2; ++it) {
      int c = it * 256 + tid;                  // [0,512)
      int key = c >> 3, dc = (c & 7) ^ (key & 7);
      g2lds16(&ks[base + (size_t)(k0 + key) * 1024 + dc * 8], &Ks[b][c * 8]);
    }
#pragma unroll
    for (int it = 0; it < 2; ++it) {
      int c = it * 256 + tid;
      int d = c >> 3, kc = (c & 7) ^ (d & 7);
      g2lds16(&vt[vtbase + (size_t)d * L + k0 + kc * 8], &Vs[b][c * 8]);
    }
  };

  const int T = L / 64;
  stage(0, 0);
  stage(1, 1);

  for (int t = 0; t < T; ++t) {
    __builtin_amdgcn_s_barrier();            // A: compute(t-1) done everywhere
    asm volatile("" ::: "memory");
    if (t + 2 < T) stage(t + 2, (t + 2) % 3);
    if (t + 2 < T)
      asm volatile("s_waitcnt vmcnt(8)" ::: "memory");
    else if (t + 1 < T)
      asm volatile("s_waitcnt vmcnt(4)" ::: "memory");
    else
      asm volatile("s_waitcnt vmcnt(0)" ::: "memory");
    __builtin_amdgcn_s_barrier();            // B: tile t visible to all
    asm volatile("" ::: "memory");

    const int cb = t % 3;
    const unsigned short* Kb = &Ks[cb][0];
    const unsigned short* Vb = &Vs[cb][0];

    // S^T = K Q^T for BOTH m-tiles; K fragments read once.
    f32x4 st[2][4];
#pragma unroll
    for (int nt = 0; nt < 4; ++nt) {
      int key = nt * 16 + l16;
      int dc0 = quad ^ (key & 7);
      int dc1 = (4 + quad) ^ (key & 7);
      bf16x8 bk0 = *reinterpret_cast<const bf16x8*>(&Kb[(key * 8 + dc0) * 8]);
      bf16x8 bk1 = *reinterpret_cast<const bf16x8*>(&Kb[(key * 8 + dc1) * 8]);
#pragma unroll
      for (int mt = 0; mt < 2; ++mt) {
        f32x4 z; z[0] = z[1] = z[2] = z[3] = 0.f;
        z = __builtin_amdgcn_mfma_f32_16x16x32_bf16(bk0, aq[mt][0], z, 0, 0, 0);
        z = __builtin_amdgcn_mfma_f32_16x16x32_bf16(bk1, aq[mt][1], z, 0, 0, 0);
        st[mt][nt] = z;
      }
    }

    // exp2 -> ap frags by pure register renaming (key-permutation sigma)
    bf16x8 ap[2][2];
#pragma unroll
    for (int mt = 0; mt < 2; ++mt) {
#pragma unroll
      for (int hf = 0; hf < 2; ++hf)
#pragma unroll
        for (int w = 0; w < 4; ++w) {
          int nt = 2 * hf + (w >> 1), p = w & 1;
          ap[mt][hf][2 * w] =
              (__bf16)__builtin_amdgcn_exp2f(st[mt][nt][2 * p]);
          ap[mt][hf][2 * w + 1] =
              (__bf16)__builtin_amdgcn_exp2f(st[mt][nt][2 * p + 1]);
        }
      lacc[mt] = __builtin_amdgcn_mfma_f32_16x16x32_bf16(ap[mt][0], ones,
                                                         lacc[mt], 0, 0, 0);
      lacc[mt] = __builtin_amdgcn_mfma_f32_16x16x32_bf16(ap[mt][1], ones,
                                                         lacc[mt], 0, 0, 0);
    }

    // O += P V (V fragments read once, reused by both m-tiles)
#pragma unroll
    for (int nt = 0; nt < 4; ++nt) {
      int d = nt * 16 + l16;
#pragma unroll
      for (int hf = 0; hf < 2; ++hf) {
        int kc = (hf * 4 + quad) ^ (d & 7);
        bf16x8 bv = *reinterpret_cast<const bf16x8*>(&Vb[(d * 8 + kc) * 8]);
#pragma unroll
        for (int mt = 0; mt < 2; ++mt)
          oacc[mt][nt] = __builtin_amdgcn_mfma_f32_16x16x32_bf16(
              ap[mt][hf], bv, oacc[mt][nt], 0, 0, 0);
      }
    }
  }

#pragma unroll
  for (int mt = 0; mt < 2; ++mt)
#pragma unroll
    for (int r = 0; r < 4; ++r) {
      float inv = __builtin_amdgcn_rcpf(lacc[mt][r]);
      int q = qb + mt * 16 + quad * 4 + r;
#pragma unroll
      for (int nt = 0; nt < 4; ++nt)
        o[base + (size_t)q * 1024 + nt * 16 + l16] =
            f2b(oacc[mt][nt][r] * inv);
    }
}

// ---------------- driver ----------------
extern "C" void kernel_launch(void* const* d_in, const int* in_sizes, int n_in,
                              void* d_out, int out_size, void* d_ws, size_t ws_size,
                              hipStream_t stream) {
  const float* X    = (const float*)d_in[0];
  const float* tq   = (const float*)d_in[1];
  const float* tk   = (const float*)d_in[2];
  const float* wkvc = (const float*)d_in[3];
  const float* wkc  = (const float*)d_in[4];
  const float* wvc  = (const float*)d_in[5];
  const float* wqr  = (const float*)d_in[6];
  const float* wkr  = (const float*)d_in[7];
  const float* wo   = (const float*)d_in[8];

  const int D = 1024, DC = 128, L = 2048;
  const int M = in_sizes[0] / D;       // B*L
  const int B = M / L;
  const int NBH = B * 16;
  (void)n_in; (void)out_size; (void)ws_size;

  unsigned short* p = (unsigned short*)d_ws;
  auto take = [&](size_t n) { unsigned short* r = p; p += n; return r; };
  unsigned short* Xb    = take((size_t)M * D);
  unsigned short* qsb   = take((size_t)M * D);
  unsigned short* ksb   = take((size_t)M * D);
  unsigned short* vcb   = take((size_t)M * D);
  unsigned short* ckv   = take((size_t)M * DC);
  unsigned short* Wbig  = take((size_t)(2 * D + DC) * D);   // [wqr|wkr|wkvc]^T
  unsigned short* Wkcvc = take((size_t)(2 * D) * DC);       // [wkc|wvc]^T
  unsigned short* WoT   = take((size_t)D * D);
  f32x2* ctab = (f32x2*)take((size_t)M * 32 * 4);           // M*32 float2
  unsigned short* vtb   = Xb;   // Xb dead after fused3 gemm; fused2 writes Vt
  unsigned short* obuf  = vcb;  // flash O lands here

  // prep: cvt + all 6 weight transposes + rope cos table in ONE launch
  const int n8 = M * D / 8;
  const int cvtb = (n8 + 255) / 256;
  const int ropeb = M / 8;             // M*32 threads / 256
  prep_kernel<<<cvtb + 864 + ropeb, 256, 0, stream>>>(
      X, Xb, cvtb, n8,
      wqr,  Wbig,
      wkr,  Wbig + (size_t)D * D,
      wkvc, Wbig + (size_t)2 * D * D,
      wkc,  Wkcvc,
      wvc,  Wkcvc + (size_t)D * DC,
      wo,   WoT,
      tq, tk, ctab);

  {
    // 1D grid 17*32 = 544 = 8*68, XCD-chunk-swizzled in-kernel
    gemm_fused3<<<(2 * D + DC) / 128 * (M / 128), 256, 0, stream>>>(
        Xb, Wbig, qsb, ksb, ckv, ctab, D);
  }
  {
    // 1D grid 16*32 = 512 = 8*64, XCD-chunk-swizzled in-kernel
    gemm_fused2<<<(2 * D / 128) * (M / 128), 256, 0, stream>>>(
        ckv, Wkcvc, ksb, vtb, DC);
  }

  dim3 fg(L / 128, NBH);                                   // (16, 32)
  flash17_kernel<<<fg, 256, 0, stream>>>(qsb, ksb, vtb, obuf, L);

  {
    // 1D grid (D/128)*(M/64) = 8*64 = 512 = 2 blocks/CU, swizzled
    gemm_bt<64, float, false><<<(D / 128) * (M / 64), 256, 0, stream>>>(
        obuf, WoT, (float*)d_out, M, D, D);
  }
}

// Round 13
// 193.006 us; speedup vs baseline: 1.0546x; 1.0324x over previous
//
#include <hip/hip_runtime.h>

typedef float          f32x4    __attribute__((ext_vector_type(4)));
typedef float          f32x2    __attribute__((ext_vector_type(2)));
typedef float          float8v  __attribute__((ext_vector_type(8)));
typedef unsigned short ushort8v __attribute__((ext_vector_type(8)));
typedef unsigned short ushort4v __attribute__((ext_vector_type(4)));
typedef __bf16         bf16x8   __attribute__((ext_vector_type(8)));

__device__ __forceinline__ unsigned short f2b(float x) {
  union { __bf16 b; unsigned short u; } v;
  v.b = (__bf16)x;                       // hw v_cvt (RNE) on gfx950
  return v.u;
}
__device__ __forceinline__ float b2f(unsigned short h) {
  union { unsigned u; float f; } v; v.u = ((unsigned)h) << 16;
  return v.f;
}

// async global->LDS, 16B per lane; LDS dest = wave-uniform base + lane*16
__device__ __forceinline__ void g2lds16(const unsigned short* g,
                                        unsigned short* l) {
  __builtin_amdgcn_global_load_lds(
      (const __attribute__((address_space(1))) unsigned int*)g,
      (__attribute__((address_space(3))) unsigned int*)l, 16, 0, 0);
}

// ---------- prep kernel: cvt + 6 weight transposes + rope cos table ------
__global__ __launch_bounds__(256) void prep_kernel(
    const float* __restrict__ X, unsigned short* __restrict__ Xb, int cvtb,
    int n8,
    const float* __restrict__ w0, unsigned short* __restrict__ t0,
    const float* __restrict__ w1, unsigned short* __restrict__ t1,
    const float* __restrict__ w2, unsigned short* __restrict__ t2,
    const float* __restrict__ w3, unsigned short* __restrict__ t3,
    const float* __restrict__ w4, unsigned short* __restrict__ t4,
    const float* __restrict__ w5, unsigned short* __restrict__ t5,
    const float* __restrict__ tq, const float* __restrict__ tk,
    f32x2* __restrict__ ctab) {
  __shared__ unsigned short T[64 * 72];
  const int tid = threadIdx.x;
  int blk = blockIdx.x;
  if (blk < cvtb) {
    int i = blk * 256 + tid;
    if (i >= n8) return;
    float8v v = reinterpret_cast<const float8v*>(X)[i];
    ushort8v h;
#pragma unroll
    for (int j = 0; j < 8; ++j) h[j] = f2b(v[j]);
    reinterpret_cast<ushort8v*>(Xb)[i] = h;
    return;
  }
  blk -= cvtb;
  if (blk >= 864) {
    // rope cos table
    int idx = (blk - 864) * 256 + tid;
    int row = idx >> 5, i = idx & 31;
    float f = exp2f(-(float)i * (13.287712379549449f / 32.f)); // 10000^(-i/32)
    f32x2 c;
    c[0] = cosf(tq[row] * f);
    c[1] = cosf(tk[row] * f);
    ctab[idx] = c;
    return;
  }
  const float* W; unsigned short* WT; int K, N, bx, by;
  if (blk < 256)      { W = w0; WT = t0; K = 1024; N = 1024; bx = blk & 15;         by = blk >> 4; }
  else if (blk < 512) { W = w1; WT = t1; K = 1024; N = 1024; bx = (blk - 256) & 15; by = (blk - 256) >> 4; }
  else if (blk < 544) { W = w2; WT = t2; K = 1024; N = 128;  bx = (blk - 512) & 1;  by = (blk - 512) >> 1; }
  else if (blk < 576) { W = w3; WT = t3; K = 128;  N = 1024; bx = (blk - 544) & 15; by = (blk - 544) >> 4; }
  else if (blk < 608) { W = w4; WT = t4; K = 128;  N = 1024; bx = (blk - 576) & 15; by = (blk - 576) >> 4; }
  else                { W = w5; WT = t5; K = 1024; N = 1024; bx = (blk - 608) & 15; by = (blk - 608) >> 4; }
  const int n0 = bx * 64, k0 = by * 64;
#pragma unroll
  for (int it = 0; it < 2; ++it) {
    int c = tid + it * 256;               // [0,512)
    int r = c >> 3, cc = c & 7;
    float8v v = *reinterpret_cast<const float8v*>(
        &W[(size_t)(k0 + r) * N + n0 + cc * 8]);
    ushort8v h;
#pragma unroll
    for (int j = 0; j < 8; ++j) h[j] = f2b(v[j]);
    *reinterpret_cast<ushort8v*>(&T[r * 72 + cc * 8]) = h;
  }
  __syncthreads();
#pragma unroll
  for (int it = 0; it < 2; ++it) {
    int c = tid + it * 256;
    int n = c >> 3, kc = c & 7;
    ushort8v y;
#pragma unroll
    for (int j = 0; j < 8; ++j) y[j] = T[(kc * 8 + j) * 72 + n];
    *reinterpret_cast<ushort8v*>(&WT[(size_t)(n0 + n) * K + k0 + kc * 8]) = y;
  }
}

// --- gemm_bt (TM=64): dbuf + counted-vmcnt pipeline, XCD-swizzled 1D grid --
// 6 staging loads/thread/stage (2 A + 4 B) -> vmcnt(6) keeps tile t+1's
// loads in flight under compute(t) (flash17-validated barrier pattern).
template <int TM, typename CT, bool ACC>
__global__ __launch_bounds__(256) void gemm_bt(
    const unsigned short* __restrict__ A, const unsigned short* __restrict__ Bt,
    CT* __restrict__ C, int M, int N, int K) {
  static_assert(TM == 64, "vmcnt literal assumes TM=64");
  __shared__ unsigned short As[2][TM * 64];
  __shared__ unsigned short Bs[2][128 * 64];
  const int tid = threadIdx.x;
  const int id = blockIdx.x, cpx = gridDim.x >> 3;
  const int swz = (id & 7) * cpx + (id >> 3);
  const int nwx = N / 128;
  const int m0 = (swz / nwx) * TM, n0 = (swz % nwx) * 128;
  const int wave = tid >> 6, lane = tid & 63;
  const int wm = (wave >> 1) * (TM / 2), wn = (wave & 1) * 64;
  const int l16 = lane & 15, quad = lane >> 4;
  constexpr int MI = TM / 32;

  f32x4 acc[MI][4];
#pragma unroll
  for (int i = 0; i < MI; ++i)
#pragma unroll
    for (int j = 0; j < 4; ++j)
#pragma unroll
      for (int r = 0; r < 4; ++r) acc[i][j][r] = 0.f;

  auto stage = [&](int k0, int b) {
#pragma unroll
    for (int it = 0; it < TM * 8 / 256; ++it) {
      int c = it * 256 + tid;
      int m = c >> 3, kc = (c & 7) ^ (m & 7);
      g2lds16(&A[(size_t)(m0 + m) * K + k0 + kc * 8], &As[b][c * 8]);
    }
#pragma unroll
    for (int it = 0; it < 4; ++it) {
      int c = it * 256 + tid;
      int n = c >> 3, kc = (c & 7) ^ (n & 7);
      g2lds16(&Bt[(size_t)(n0 + n) * K + k0 + kc * 8], &Bs[b][c * 8]);
    }
  };

  const int T = K / 64;
  stage(0, 0);
  for (int t = 0; t < T; ++t) {
    __builtin_amdgcn_s_barrier();          // compute(t-1) done; buf free
    asm volatile("" ::: "memory");
    if (t + 1 < T) {
      stage((t + 1) * 64, (t + 1) & 1);
      asm volatile("s_waitcnt vmcnt(6)" ::: "memory");  // tile t resident
    } else {
      asm volatile("s_waitcnt vmcnt(0)" ::: "memory");
    }
    __builtin_amdgcn_s_barrier();          // tile t visible to all
    asm volatile("" ::: "memory");
    const int cb = t & 1;

#pragma unroll
    for (int ks = 0; ks < 2; ++ks) {
      bf16x8 af[MI], bfr[4];
#pragma unroll
      for (int mi = 0; mi < MI; ++mi) {
        int m = wm + mi * 16 + l16;
        af[mi] = *reinterpret_cast<const bf16x8*>(
            &As[cb][(m * 8 + ((ks * 4 + quad) ^ (m & 7))) * 8]);
      }
#pragma unroll
      for (int ni = 0; ni < 4; ++ni) {
        int n = wn + ni * 16 + l16;
        bfr[ni] = *reinterpret_cast<const bf16x8*>(
            &Bs[cb][(n * 8 + ((ks * 4 + quad) ^ (n & 7))) * 8]);
      }
#pragma unroll
      for (int mi = 0; mi < MI; ++mi)
#pragma unroll
        for (int ni = 0; ni < 4; ++ni)
          acc[mi][ni] = __builtin_amdgcn_mfma_f32_16x16x32_bf16(
              af[mi], bfr[ni], acc[mi][ni], 0, 0, 0);
    }
  }

#pragma unroll
  for (int mi = 0; mi < MI; ++mi)
#pragma unroll
    for (int ni = 0; ni < 4; ++ni) {
      int row = m0 + wm + mi * 16 + quad * 4;
      int col = n0 + wn + ni * 16 + l16;
#pragma unroll
      for (int r = 0; r < 4; ++r) {
        size_t idx = (size_t)(row + r) * N + col;
        float val = acc[mi][ni][r];
        if constexpr (sizeof(CT) == 2) {
          if constexpr (ACC) val += b2f(C[idx]);
          C[idx] = f2b(val);
        } else {
          if constexpr (ACC) val += C[idx];
          C[idx] = val;
        }
      }
    }
}

// -- fused GEMM #1 + rope: [q_r|k_r|c_kv] = X @ [wqr|wkr|wkvc]^T ----------
// dbuf + counted vmcnt(8) (8 loads/thread/stage). Rope epilogue from
// PRECOMPUTED cos table (R8 lesson). 1D grid 544 = 8*68 XCD-swizzled.
__global__ __launch_bounds__(256) void gemm_fused3(
    const unsigned short* __restrict__ A, const unsigned short* __restrict__ Bt,
    unsigned short* __restrict__ Cq, unsigned short* __restrict__ Ck,
    unsigned short* __restrict__ Cc, const f32x2* __restrict__ ctab, int K) {
  __shared__ unsigned short As[2][1024 * 8];
  __shared__ unsigned short Bs[2][1024 * 8];
  const int tid = threadIdx.x;
  const int id = blockIdx.x;
  const int swz = (id & 7) * 68 + (id >> 3);          // 544 = 8*68 bijective
  const int m0 = (swz / 17) * 128, n0 = (swz % 17) * 128;
  const int wave = tid >> 6, lane = tid & 63;
  const int wm = (wave >> 1) * 64, wn = (wave & 1) * 64;
  const int l16 = lane & 15, quad = lane >> 4;

  f32x4 acc[4][4];
#pragma unroll
  for (int i = 0; i < 4; ++i)
#pragma unroll
    for (int j = 0; j < 4; ++j)
#pragma unroll
      for (int r = 0; r < 4; ++r) acc[i][j][r] = 0.f;

  auto stage = [&](int k0, int b) {
#pragma unroll
    for (int it = 0; it < 4; ++it) {
      int c = it * 256 + tid;
      int m = c >> 3, kc = (c & 7) ^ (m & 7);
      g2lds16(&A[(size_t)(m0 + m) * K + k0 + kc * 8], &As[b][c * 8]);
    }
#pragma unroll
    for (int it = 0; it < 4; ++it) {
      int c = it * 256 + tid;
      int n = c >> 3, kc = (c & 7) ^ (n & 7);
      g2lds16(&Bt[(size_t)(n0 + n) * K + k0 + kc * 8], &Bs[b][c * 8]);
    }
  };

  const int T = K / 64;
  stage(0, 0);
  for (int t = 0; t < T; ++t) {
    __builtin_amdgcn_s_barrier();
    asm volatile("" ::: "memory");
    if (t + 1 < T) {
      stage((t + 1) * 64, (t + 1) & 1);
      asm volatile("s_waitcnt vmcnt(8)" ::: "memory");
    } else {
      asm volatile("s_waitcnt vmcnt(0)" ::: "memory");
    }
    __builtin_amdgcn_s_barrier();
    asm volatile("" ::: "memory");
    const int cb = t & 1;

#pragma unroll
    for (int ks = 0; ks < 2; ++ks) {
      bf16x8 af[4], bfr[4];
#pragma unroll
      for (int mi = 0; mi < 4; ++mi) {
        int m = wm + mi * 16 + l16;
        af[mi] = *reinterpret_cast<const bf16x8*>(
            &As[cb][(m * 8 + ((ks * 4 + quad) ^ (m & 7))) * 8]);
      }
#pragma unroll
      for (int ni = 0; ni < 4; ++ni) {
        int n = wn + ni * 16 + l16;
        bfr[ni] = *reinterpret_cast<const bf16x8*>(
            &Bs[cb][(n * 8 + ((ks * 4 + quad) ^ (n & 7))) * 8]);
      }
#pragma unroll
      for (int mi = 0; mi < 4; ++mi)
#pragma unroll
        for (int ni = 0; ni < 4; ++ni)
          acc[mi][ni] = __builtin_amdgcn_mfma_f32_16x16x32_bf16(
              af[mi], bfr[ni], acc[mi][ni], 0, 0, 0);
    }
  }

  if (n0 < 2048) {
    // rope path (q or k): cq/ck from table, pure FMA epilogue
    const bool isq = (n0 < 1024);
    unsigned short* dst = isq ? Cq : Ck;
    const int cb = isq ? 0 : 1024;
    const float s = isq ? 0.18033688011112042f : 1.0f;  // 0.125*log2(e) | 1
#pragma unroll
    for (int mi = 0; mi < 4; ++mi)
#pragma unroll
      for (int r = 0; r < 4; ++r) {
        int row = m0 + wm + mi * 16 + quad * 4 + r;
        const f32x2* crow = &ctab[(size_t)row * 32];
#pragma unroll
        for (int np = 0; np < 2; ++np) {
          f32x2 cc = crow[np * 16 + l16];        // {cq, ck}
          float v1 = acc[mi][np][r], v2 = acc[mi][np + 2][r];
          int col = n0 - cb + wn + np * 16 + l16;
          dst[(size_t)row * 1024 + col]      = f2b((v1 * cc[0] - v2 * cc[1]) * s);
          dst[(size_t)row * 1024 + col + 32] = f2b((v2 * cc[0] + v1 * cc[1]) * s);
        }
      }
  } else {
    // c_kv plain store
#pragma unroll
    for (int mi = 0; mi < 4; ++mi)
#pragma unroll
      for (int ni = 0; ni < 4; ++ni) {
        int row = m0 + wm + mi * 16 + quad * 4;
        int col = n0 - 2048 + wn + ni * 16 + l16;
#pragma unroll
        for (int r = 0; r < 4; ++r)
          Cc[(size_t)(row + r) * 128 + col] = f2b(acc[mi][ni][r]);
      }
  }
}

// ------- fused GEMM #2: [k_c(acc->ksb) | v_c -> Vt direct] ---------------
// dbuf + counted vmcnt(8); k_c accumulates onto rope'd k_r; v_c stored
// directly into sigma^-1-permuted Vt (8B stores). 1D grid 512 swizzled.
__global__ __launch_bounds__(256) void gemm_fused2(
    const unsigned short* __restrict__ A, const unsigned short* __restrict__ Bt,
    unsigned short* __restrict__ Ck, unsigned short* __restrict__ vt, int K) {
  __shared__ unsigned short As[2][1024 * 8];
  __shared__ unsigned short Bs[2][1024 * 8];
  const int tid = threadIdx.x;
  const int id = blockIdx.x;
  const int swz = (id & 7) * 64 + (id >> 3);          // 512 = 8*64 bijective
  const int m0 = (swz >> 4) * 128, n0 = (swz & 15) * 128;
  const int wave = tid >> 6, lane = tid & 63;
  const int wm = (wave >> 1) * 64, wn = (wave & 1) * 64;
  const int l16 = lane & 15, quad = lane >> 4;

  f32x4 acc[4][4];
#pragma unroll
  for (int i = 0; i < 4; ++i)
#pragma unroll
    for (int j = 0; j < 4; ++j)
#pragma unroll
      for (int r = 0; r < 4; ++r) acc[i][j][r] = 0.f;

  auto stage = [&](int k0, int b) {
#pragma unroll
    for (int it = 0; it < 4; ++it) {
      int c = it * 256 + tid;
      int m = c >> 3, kc = (c & 7) ^ (m & 7);
      g2lds16(&A[(size_t)(m0 + m) * K + k0 + kc * 8], &As[b][c * 8]);
    }
#pragma unroll
    for (int it = 0; it < 4; ++it) {
      int c = it * 256 + tid;
      int n = c >> 3, kc = (c & 7) ^ (n & 7);
      g2lds16(&Bt[(size_t)(n0 + n) * K + k0 + kc * 8], &Bs[b][c * 8]);
    }
  };

  const int T = K / 64;
  stage(0, 0);
  for (int t = 0; t < T; ++t) {
    __builtin_amdgcn_s_barrier();
    asm volatile("" ::: "memory");
    if (t + 1 < T) {
      stage((t + 1) * 64, (t + 1) & 1);
      asm volatile("s_waitcnt vmcnt(8)" ::: "memory");
    } else {
      asm volatile("s_waitcnt vmcnt(0)" ::: "memory");
    }
    __builtin_amdgcn_s_barrier();
    asm volatile("" ::: "memory");
    const int cb = t & 1;

#pragma unroll
    for (int ks = 0; ks < 2; ++ks) {
      bf16x8 af[4], bfr[4];
#pragma unroll
      for (int mi = 0; mi < 4; ++mi) {
        int m = wm + mi * 16 + l16;
        af[mi] = *reinterpret_cast<const bf16x8*>(
            &As[cb][(m * 8 + ((ks * 4 + quad) ^ (m & 7))) * 8]);
      }
#pragma unroll
      for (int ni = 0; ni < 4; ++ni) {
        int n = wn + ni * 16 + l16;
        bfr[ni] = *reinterpret_cast<const bf16x8*>(
            &Bs[cb][(n * 8 + ((ks * 4 + quad) ^ (n & 7))) * 8]);
      }
#pragma unroll
      for (int mi = 0; mi < 4; ++mi)
#pragma unroll
        for (int ni = 0; ni < 4; ++ni)
          acc[mi][ni] = __builtin_amdgcn_mfma_f32_16x16x32_bf16(
              af[mi], bfr[ni], acc[mi][ni], 0, 0, 0);
    }
  }

  if (n0 < 1024) {
    // k_c: accumulate onto rope'd k_r
#pragma unroll
    for (int mi = 0; mi < 4; ++mi)
#pragma unroll
      for (int ni = 0; ni < 4; ++ni) {
        int row = m0 + wm + mi * 16 + quad * 4;
        int col = n0 + wn + ni * 16 + l16;
#pragma unroll
        for (int r = 0; r < 4; ++r) {
          size_t idx = (size_t)(row + r) * 1024 + col;
          Ck[idx] = f2b(acc[mi][ni][r] + b2f(Ck[idx]));
        }
      }
  } else {
    // v_c -> Vt[b,h,d,sigma^-1(l)] direct, 8B stores
    const int L = 2048;
#pragma unroll
    for (int mi = 0; mi < 4; ++mi)
#pragma unroll
      for (int ni = 0; ni < 4; ++ni) {
        int row = m0 + wm + mi * 16 + quad * 4;       // row % 4 == 0
        int col = n0 - 1024 + wn + ni * 16 + l16;     // h*64 + d
        int l = row & (L - 1);
        int bh = ((row >> 11) << 4) | (col >> 6);
        int d = col & 63;
        int s = (l & ~63) | (((l >> 5) & 1) << 5) | (((l >> 3) & 1) << 4) |
                (((l >> 2) & 1) << 3) | (((l >> 4) & 1) << 2);
        ushort4v w;
#pragma unroll
        for (int r = 0; r < 4; ++r) w[r] = f2b(acc[mi][ni][r]);
        *reinterpret_cast<ushort4v*>(
            &vt[(size_t)bh * 64 * L + (size_t)d * L + s]) = w;
      }
  }
}

// ---------- flash v17: 4 waves x 32q + 3-buffer counted-vmcnt (T4) --------
__global__ __launch_bounds__(256, 3) void flash17_kernel(
    const unsigned short* __restrict__ qs, const unsigned short* __restrict__ ks,
    const unsigned short* __restrict__ vt, unsigned short* __restrict__ o,
    int L) {
  __shared__ unsigned short Ks[3][512 * 8];   // 64 key x 64 d, swizzled
  __shared__ unsigned short Vs[3][512 * 8];   // 64 d x 64 key(perm), swizzled
  const int tid = threadIdx.x;
  const int wave = tid >> 6, lane = tid & 63;
  const int l16 = lane & 15, quad = lane >> 4;
  const int bh = blockIdx.y;                   // b*16 + h
  const int qb = blockIdx.x * 128 + wave * 32; // this wave's 32 q rows
  const size_t base = ((size_t)(bh >> 4) * L) * 1024 + (bh & 15) * 64;
  const size_t vtbase = (size_t)bh * 64 * L;

  bf16x8 aq[2][2];
#pragma unroll
  for (int mt = 0; mt < 2; ++mt) {
    size_t qrow = base + (size_t)(qb + mt * 16 + l16) * 1024;
    aq[mt][0] = *reinterpret_cast<const bf16x8*>(&qs[qrow + quad * 8]);
    aq[mt][1] = *reinterpret_cast<const bf16x8*>(&qs[qrow + 32 + quad * 8]);
  }

  ushort8v onesu;
#pragma unroll
  for (int j = 0; j < 8; ++j) onesu[j] = 0x3F80;  // bf16 1.0
  bf16x8 ones = *reinterpret_cast<bf16x8*>(&onesu);

  f32x4 oacc[2][4];
  f32x4 lacc[2];
#pragma unroll
  for (int mt = 0; mt < 2; ++mt) {
#pragma unroll
    for (int r = 0; r < 4; ++r) lacc[mt][r] = 0.f;
#pragma unroll
    for (int nt = 0; nt < 4; ++nt)
#pragma unroll
      for (int r = 0; r < 4; ++r) oacc[mt][nt][r] = 0.f;
  }

  auto stage = [&](int t, int b) {
    int k0 = t * 64;
#pragma unroll
    for (int it = 0; it < 2; ++it) {
      int c = it * 256 + tid;                  // [0,512)
      int key = c >> 3, dc = (c & 7) ^ (key & 7);
      g2lds16(&ks[base + (size_t)(k0 + key) * 1024 + dc * 8], &Ks[b][c * 8]);
    }
#pragma unroll
    for (int it = 0; it < 2; ++it) {
      int c = it * 256 + tid;
      int d = c >> 3, kc = (c & 7) ^ (d & 7);
      g2lds16(&vt[vtbase + (size_t)d * L + k0 + kc * 8], &Vs[b][c * 8]);
    }
  };

  const int T = L / 64;
  stage(0, 0);
  stage(1, 1);

  for (int t = 0; t < T; ++t) {
    __builtin_amdgcn_s_barrier();            // A: compute(t-1) done everywhere
    asm volatile("" ::: "memory");
    if (t + 2 < T) stage(t + 2, (t + 2) % 3);
    if (t + 2 < T)
      asm volatile("s_waitcnt vmcnt(8)" ::: "memory");
    else if (t + 1 < T)
      asm volatile("s_waitcnt vmcnt(4)" ::: "memory");
    else
      asm volatile("s_waitcnt vmcnt(0)" ::: "memory");
    __builtin_amdgcn_s_barrier();            // B: tile t visible to all
    asm volatile("" ::: "memory");

    const int cb = t % 3;
    const unsigned short* Kb = &Ks[cb][0];
    const unsigned short* Vb = &Vs[cb][0];

    // S^T = K Q^T for BOTH m-tiles; K fragments read once.
    f32x4 st[2][4];
#pragma unroll
    for (int nt = 0; nt < 4; ++nt) {
      int key = nt * 16 + l16;
      int dc0 = quad ^ (key & 7);
      int dc1 = (4 + quad) ^ (key & 7);
      bf16x8 bk0 = *reinterpret_cast<const bf16x8*>(&Kb[(key * 8 + dc0) * 8]);
      bf16x8 bk1 = *reinterpret_cast<const bf16x8*>(&Kb[(key * 8 + dc1) * 8]);
#pragma unroll
      for (int mt = 0; mt < 2; ++mt) {
        f32x4 z; z[0] = z[1] = z[2] = z[3] = 0.f;
        z = __builtin_amdgcn_mfma_f32_16x16x32_bf16(bk0, aq[mt][0], z, 0, 0, 0);
        z = __builtin_amdgcn_mfma_f32_16x16x32_bf16(bk1, aq[mt][1], z, 0, 0, 0);
        st[mt][nt] = z;
      }
    }

    // exp2 -> ap frags by pure register renaming (key-permutation sigma)
    bf16x8 ap[2][2];
#pragma unroll
    for (int mt = 0; mt < 2; ++mt) {
#pragma unroll
      for (int hf = 0; hf < 2; ++hf)
#pragma unroll
        for (int w = 0; w < 4; ++w) {
          int nt = 2 * hf + (w >> 1), p = w & 1;
          ap[mt][hf][2 * w] =
              (__bf16)__builtin_amdgcn_exp2f(st[mt][nt][2 * p]);
          ap[mt][hf][2 * w + 1] =
              (__bf16)__builtin_amdgcn_exp2f(st[mt][nt][2 * p + 1]);
        }
      lacc[mt] = __builtin_amdgcn_mfma_f32_16x16x32_bf16(ap[mt][0], ones,
                                                         lacc[mt], 0, 0, 0);
      lacc[mt] = __builtin_amdgcn_mfma_f32_16x16x32_bf16(ap[mt][1], ones,
                                                         lacc[mt], 0, 0, 0);
    }

    // O += P V (V fragments read once, reused by both m-tiles)
#pragma unroll
    for (int nt = 0; nt < 4; ++nt) {
      int d = nt * 16 + l16;
#pragma unroll
      for (int hf = 0; hf < 2; ++hf) {
        int kc = (hf * 4 + quad) ^ (d & 7);
        bf16x8 bv = *reinterpret_cast<const bf16x8*>(&Vb[(d * 8 + kc) * 8]);
#pragma unroll
        for (int mt = 0; mt < 2; ++mt)
          oacc[mt][nt] = __builtin_amdgcn_mfma_f32_16x16x32_bf16(
              ap[mt][hf], bv, oacc[mt][nt], 0, 0, 0);
      }
    }
  }

#pragma unroll
  for (int mt = 0; mt < 2; ++mt)
#pragma unroll
    for (int r = 0; r < 4; ++r) {
      float inv = __builtin_amdgcn_rcpf(lacc[mt][r]);
      int q = qb + mt * 16 + quad * 4 + r;
#pragma unroll
      for (int nt = 0; nt < 4; ++nt)
        o[base + (size_t)q * 1024 + nt * 16 + l16] =
            f2b(oacc[mt][nt][r] * inv);
    }
}

// ---------------- driver ----------------
extern "C" void kernel_launch(void* const* d_in, const int* in_sizes, int n_in,
                              void* d_out, int out_size, void* d_ws, size_t ws_size,
                              hipStream_t stream) {
  const float* X    = (const float*)d_in[0];
  const float* tq   = (const float*)d_in[1];
  const float* tk   = (const float*)d_in[2];
  const float* wkvc = (const float*)d_in[3];
  const float* wkc  = (const float*)d_in[4];
  const float* wvc  = (const float*)d_in[5];
  const float* wqr  = (const float*)d_in[6];
  const float* wkr  = (const float*)d_in[7];
  const float* wo   = (const float*)d_in[8];

  const int D = 1024, DC = 128, L = 2048;
  const int M = in_sizes[0] / D;       // B*L
  const int B = M / L;
  const int NBH = B * 16;
  (void)n_in; (void)out_size; (void)ws_size;

  unsigned short* p = (unsigned short*)d_ws;
  auto take = [&](size_t n) { unsigned short* r = p; p += n; return r; };
  unsigned short* Xb    = take((size_t)M * D);
  unsigned short* qsb   = take((size_t)M * D);
  unsigned short* ksb   = take((size_t)M * D);
  unsigned short* vcb   = take((size_t)M * D);
  unsigned short* ckv   = take((size_t)M * DC);
  unsigned short* Wbig  = take((size_t)(2 * D + DC) * D);   // [wqr|wkr|wkvc]^T
  unsigned short* Wkcvc = take((size_t)(2 * D) * DC);       // [wkc|wvc]^T
  unsigned short* WoT   = take((size_t)D * D);
  f32x2* ctab = (f32x2*)take((size_t)M * 32 * 4);           // M*32 float2
  unsigned short* vtb   = Xb;   // Xb dead after fused3 gemm; fused2 writes Vt
  unsigned short* obuf  = vcb;  // flash O lands here

  // prep: cvt + all 6 weight transposes + rope cos table in ONE launch
  const int n8 = M * D / 8;
  const int cvtb = (n8 + 255) / 256;
  const int ropeb = M / 8;             // M*32 threads / 256
  prep_kernel<<<cvtb + 864 + ropeb, 256, 0, stream>>>(
      X, Xb, cvtb, n8,
      wqr,  Wbig,
      wkr,  Wbig + (size_t)D * D,
      wkvc, Wbig + (size_t)2 * D * D,
      wkc,  Wkcvc,
      wvc,  Wkcvc + (size_t)D * DC,
      wo,   WoT,
      tq, tk, ctab);

  {
    // 1D grid 17*32 = 544 = 8*68, XCD-chunk-swizzled in-kernel
    gemm_fused3<<<(2 * D + DC) / 128 * (M / 128), 256, 0, stream>>>(
        Xb, Wbig, qsb, ksb, ckv, ctab, D);
  }
  {
    // 1D grid 16*32 = 512 = 8*64, XCD-chunk-swizzled in-kernel
    gemm_fused2<<<(2 * D / 128) * (M / 128), 256, 0, stream>>>(
        ckv, Wkcvc, ksb, vtb, DC);
  }

  dim3 fg(L / 128, NBH);                                   // (16, 32)
  flash17_kernel<<<fg, 256, 0, stream>>>(qsb, ksb, vtb, obuf, L);

  {
    // 1D grid (D/128)*(M/64) = 8*64 = 512 = 2 blocks/CU, swizzled
    gemm_bt<64, float, false><<<(D / 128) * (M / 64), 256, 0, stream>>>(
        obuf, WoT, (float*)d_out, M, D, D);
  }
}

// Round 14
// 191.462 us; speedup vs baseline: 1.0631x; 1.0081x over previous
//
#include <hip/hip_runtime.h>

typedef float          f32x4    __attribute__((ext_vector_type(4)));
typedef float          f32x2    __attribute__((ext_vector_type(2)));
typedef float          float8v  __attribute__((ext_vector_type(8)));
typedef unsigned short ushort8v __attribute__((ext_vector_type(8)));
typedef unsigned short ushort4v __attribute__((ext_vector_type(4)));
typedef __bf16         bf16x8   __attribute__((ext_vector_type(8)));

__device__ __forceinline__ unsigned short f2b(float x) {
  union { __bf16 b; unsigned short u; } v;
  v.b = (__bf16)x;                       // hw v_cvt (RNE) on gfx950
  return v.u;
}
__device__ __forceinline__ float b2f(unsigned short h) {
  union { unsigned u; float f; } v; v.u = ((unsigned)h) << 16;
  return v.f;
}

// async global->LDS, 16B per lane; LDS dest = wave-uniform base + lane*16
__device__ __forceinline__ void g2lds16(const unsigned short* g,
                                        unsigned short* l) {
  __builtin_amdgcn_global_load_lds(
      (const __attribute__((address_space(1))) unsigned int*)g,
      (__attribute__((address_space(3))) unsigned int*)l, 16, 0, 0);
}

// ---------- prep kernel: cvt + 6 weight transposes + rope cos table ------
__global__ __launch_bounds__(256) void prep_kernel(
    const float* __restrict__ X, unsigned short* __restrict__ Xb, int cvtb,
    int n8,
    const float* __restrict__ w0, unsigned short* __restrict__ t0,
    const float* __restrict__ w1, unsigned short* __restrict__ t1,
    const float* __restrict__ w2, unsigned short* __restrict__ t2,
    const float* __restrict__ w3, unsigned short* __restrict__ t3,
    const float* __restrict__ w4, unsigned short* __restrict__ t4,
    const float* __restrict__ w5, unsigned short* __restrict__ t5,
    const float* __restrict__ tq, const float* __restrict__ tk,
    f32x2* __restrict__ ctab) {
  __shared__ unsigned short T[64 * 72];
  const int tid = threadIdx.x;
  int blk = blockIdx.x;
  if (blk < cvtb) {
    int i = blk * 256 + tid;
    if (i >= n8) return;
    float8v v = reinterpret_cast<const float8v*>(X)[i];
    ushort8v h;
#pragma unroll
    for (int j = 0; j < 8; ++j) h[j] = f2b(v[j]);
    reinterpret_cast<ushort8v*>(Xb)[i] = h;
    return;
  }
  blk -= cvtb;
  if (blk >= 864) {
    // rope cos table
    int idx = (blk - 864) * 256 + tid;
    int row = idx >> 5, i = idx & 31;
    float f = exp2f(-(float)i * (13.287712379549449f / 32.f)); // 10000^(-i/32)
    f32x2 c;
    c[0] = cosf(tq[row] * f);
    c[1] = cosf(tk[row] * f);
    ctab[idx] = c;
    return;
  }
  const float* W; unsigned short* WT; int K, N, bx, by;
  if (blk < 256)      { W = w0; WT = t0; K = 1024; N = 1024; bx = blk & 15;         by = blk >> 4; }
  else if (blk < 512) { W = w1; WT = t1; K = 1024; N = 1024; bx = (blk - 256) & 15; by = (blk - 256) >> 4; }
  else if (blk < 544) { W = w2; WT = t2; K = 1024; N = 128;  bx = (blk - 512) & 1;  by = (blk - 512) >> 1; }
  else if (blk < 576) { W = w3; WT = t3; K = 128;  N = 1024; bx = (blk - 544) & 15; by = (blk - 544) >> 4; }
  else if (blk < 608) { W = w4; WT = t4; K = 128;  N = 1024; bx = (blk - 576) & 15; by = (blk - 576) >> 4; }
  else                { W = w5; WT = t5; K = 1024; N = 1024; bx = (blk - 608) & 15; by = (blk - 608) >> 4; }
  const int n0 = bx * 64, k0 = by * 64;
#pragma unroll
  for (int it = 0; it < 2; ++it) {
    int c = tid + it * 256;               // [0,512)
    int r = c >> 3, cc = c & 7;
    float8v v = *reinterpret_cast<const float8v*>(
        &W[(size_t)(k0 + r) * N + n0 + cc * 8]);
    ushort8v h;
#pragma unroll
    for (int j = 0; j < 8; ++j) h[j] = f2b(v[j]);
    *reinterpret_cast<ushort8v*>(&T[r * 72 + cc * 8]) = h;
  }
  __syncthreads();
#pragma unroll
  for (int it = 0; it < 2; ++it) {
    int c = tid + it * 256;
    int n = c >> 3, kc = c & 7;
    ushort8v y;
#pragma unroll
    for (int j = 0; j < 8; ++j) y[j] = T[(kc * 8 + j) * 72 + n];
    *reinterpret_cast<ushort8v*>(&WT[(size_t)(n0 + n) * K + k0 + kc * 8]) = y;
  }
}

// --- gemm_bt (TM=64): dbuf + counted-vmcnt pipeline, XCD-swizzled 1D grid --
template <int TM, typename CT, bool ACC>
__global__ __launch_bounds__(256) void gemm_bt(
    const unsigned short* __restrict__ A, const unsigned short* __restrict__ Bt,
    CT* __restrict__ C, int M, int N, int K) {
  static_assert(TM == 64, "vmcnt literal assumes TM=64");
  __shared__ unsigned short As[2][TM * 64];
  __shared__ unsigned short Bs[2][128 * 64];
  const int tid = threadIdx.x;
  const int id = blockIdx.x, cpx = gridDim.x >> 3;
  const int swz = (id & 7) * cpx + (id >> 3);
  const int nwx = N / 128;
  const int m0 = (swz / nwx) * TM, n0 = (swz % nwx) * 128;
  const int wave = tid >> 6, lane = tid & 63;
  const int wm = (wave >> 1) * (TM / 2), wn = (wave & 1) * 64;
  const int l16 = lane & 15, quad = lane >> 4;
  constexpr int MI = TM / 32;

  f32x4 acc[MI][4];
#pragma unroll
  for (int i = 0; i < MI; ++i)
#pragma unroll
    for (int j = 0; j < 4; ++j)
#pragma unroll
      for (int r = 0; r < 4; ++r) acc[i][j][r] = 0.f;

  auto stage = [&](int k0, int b) {
#pragma unroll
    for (int it = 0; it < TM * 8 / 256; ++it) {
      int c = it * 256 + tid;
      int m = c >> 3, kc = (c & 7) ^ (m & 7);
      g2lds16(&A[(size_t)(m0 + m) * K + k0 + kc * 8], &As[b][c * 8]);
    }
#pragma unroll
    for (int it = 0; it < 4; ++it) {
      int c = it * 256 + tid;
      int n = c >> 3, kc = (c & 7) ^ (n & 7);
      g2lds16(&Bt[(size_t)(n0 + n) * K + k0 + kc * 8], &Bs[b][c * 8]);
    }
  };

  const int T = K / 64;
  stage(0, 0);
  for (int t = 0; t < T; ++t) {
    __builtin_amdgcn_s_barrier();          // compute(t-1) done; buf free
    asm volatile("" ::: "memory");
    if (t + 1 < T) {
      stage((t + 1) * 64, (t + 1) & 1);
      asm volatile("s_waitcnt vmcnt(6)" ::: "memory");  // tile t resident
    } else {
      asm volatile("s_waitcnt vmcnt(0)" ::: "memory");
    }
    __builtin_amdgcn_s_barrier();          // tile t visible to all
    asm volatile("" ::: "memory");
    const int cb = t & 1;

#pragma unroll
    for (int ks = 0; ks < 2; ++ks) {
      bf16x8 af[MI], bfr[4];
#pragma unroll
      for (int mi = 0; mi < MI; ++mi) {
        int m = wm + mi * 16 + l16;
        af[mi] = *reinterpret_cast<const bf16x8*>(
            &As[cb][(m * 8 + ((ks * 4 + quad) ^ (m & 7))) * 8]);
      }
#pragma unroll
      for (int ni = 0; ni < 4; ++ni) {
        int n = wn + ni * 16 + l16;
        bfr[ni] = *reinterpret_cast<const bf16x8*>(
            &Bs[cb][(n * 8 + ((ks * 4 + quad) ^ (n & 7))) * 8]);
      }
#pragma unroll
      for (int mi = 0; mi < MI; ++mi)
#pragma unroll
        for (int ni = 0; ni < 4; ++ni)
          acc[mi][ni] = __builtin_amdgcn_mfma_f32_16x16x32_bf16(
              af[mi], bfr[ni], acc[mi][ni], 0, 0, 0);
    }
  }

#pragma unroll
  for (int mi = 0; mi < MI; ++mi)
#pragma unroll
    for (int ni = 0; ni < 4; ++ni) {
      int row = m0 + wm + mi * 16 + quad * 4;
      int col = n0 + wn + ni * 16 + l16;
#pragma unroll
      for (int r = 0; r < 4; ++r) {
        size_t idx = (size_t)(row + r) * N + col;
        float val = acc[mi][ni][r];
        if constexpr (sizeof(CT) == 2) {
          if constexpr (ACC) val += b2f(C[idx]);
          C[idx] = f2b(val);
        } else {
          if constexpr (ACC) val += C[idx];
          C[idx] = val;
        }
      }
    }
}

// -- fused GEMM #1 + rope: [q_r|k_r|c_kv] = X @ [wqr|wkr|wkvc]^T ----------
// dbuf + counted vmcnt(8). Rope epilogue from PRECOMPUTED cos table (R8
// lesson). 1D grid 544 = 8*68 XCD-swizzled.
__global__ __launch_bounds__(256) void gemm_fused3(
    const unsigned short* __restrict__ A, const unsigned short* __restrict__ Bt,
    unsigned short* __restrict__ Cq, unsigned short* __restrict__ Ck,
    unsigned short* __restrict__ Cc, const f32x2* __restrict__ ctab, int K) {
  __shared__ unsigned short As[2][1024 * 8];
  __shared__ unsigned short Bs[2][1024 * 8];
  const int tid = threadIdx.x;
  const int id = blockIdx.x;
  const int swz = (id & 7) * 68 + (id >> 3);          // 544 = 8*68 bijective
  const int m0 = (swz / 17) * 128, n0 = (swz % 17) * 128;
  const int wave = tid >> 6, lane = tid & 63;
  const int wm = (wave >> 1) * 64, wn = (wave & 1) * 64;
  const int l16 = lane & 15, quad = lane >> 4;

  f32x4 acc[4][4];
#pragma unroll
  for (int i = 0; i < 4; ++i)
#pragma unroll
    for (int j = 0; j < 4; ++j)
#pragma unroll
      for (int r = 0; r < 4; ++r) acc[i][j][r] = 0.f;

  auto stage = [&](int k0, int b) {
#pragma unroll
    for (int it = 0; it < 4; ++it) {
      int c = it * 256 + tid;
      int m = c >> 3, kc = (c & 7) ^ (m & 7);
      g2lds16(&A[(size_t)(m0 + m) * K + k0 + kc * 8], &As[b][c * 8]);
    }
#pragma unroll
    for (int it = 0; it < 4; ++it) {
      int c = it * 256 + tid;
      int n = c >> 3, kc = (c & 7) ^ (n & 7);
      g2lds16(&Bt[(size_t)(n0 + n) * K + k0 + kc * 8], &Bs[b][c * 8]);
    }
  };

  const int T = K / 64;
  stage(0, 0);
  for (int t = 0; t < T; ++t) {
    __builtin_amdgcn_s_barrier();
    asm volatile("" ::: "memory");
    if (t + 1 < T) {
      stage((t + 1) * 64, (t + 1) & 1);
      asm volatile("s_waitcnt vmcnt(8)" ::: "memory");
    } else {
      asm volatile("s_waitcnt vmcnt(0)" ::: "memory");
    }
    __builtin_amdgcn_s_barrier();
    asm volatile("" ::: "memory");
    const int cb = t & 1;

#pragma unroll
    for (int ks = 0; ks < 2; ++ks) {
      bf16x8 af[4], bfr[4];
#pragma unroll
      for (int mi = 0; mi < 4; ++mi) {
        int m = wm + mi * 16 + l16;
        af[mi] = *reinterpret_cast<const bf16x8*>(
            &As[cb][(m * 8 + ((ks * 4 + quad) ^ (m & 7))) * 8]);
      }
#pragma unroll
      for (int ni = 0; ni < 4; ++ni) {
        int n = wn + ni * 16 + l16;
        bfr[ni] = *reinterpret_cast<const bf16x8*>(
            &Bs[cb][(n * 8 + ((ks * 4 + quad) ^ (n & 7))) * 8]);
      }
#pragma unroll
      for (int mi = 0; mi < 4; ++mi)
#pragma unroll
        for (int ni = 0; ni < 4; ++ni)
          acc[mi][ni] = __builtin_amdgcn_mfma_f32_16x16x32_bf16(
              af[mi], bfr[ni], acc[mi][ni], 0, 0, 0);
    }
  }

  if (n0 < 2048) {
    // rope path (q or k): cq/ck from table, pure FMA epilogue
    const bool isq = (n0 < 1024);
    unsigned short* dst = isq ? Cq : Ck;
    const int cb = isq ? 0 : 1024;
    const float s = isq ? 0.18033688011112042f : 1.0f;  // 0.125*log2(e) | 1
#pragma unroll
    for (int mi = 0; mi < 4; ++mi)
#pragma unroll
      for (int r = 0; r < 4; ++r) {
        int row = m0 + wm + mi * 16 + quad * 4 + r;
        const f32x2* crow = &ctab[(size_t)row * 32];
#pragma unroll
        for (int np = 0; np < 2; ++np) {
          f32x2 cc = crow[np * 16 + l16];        // {cq, ck}
          float v1 = acc[mi][np][r], v2 = acc[mi][np + 2][r];
          int col = n0 - cb + wn + np * 16 + l16;
          dst[(size_t)row * 1024 + col]      = f2b((v1 * cc[0] - v2 * cc[1]) * s);
          dst[(size_t)row * 1024 + col + 32] = f2b((v2 * cc[0] + v1 * cc[1]) * s);
        }
      }
  } else {
    // c_kv plain store
#pragma unroll
    for (int mi = 0; mi < 4; ++mi)
#pragma unroll
      for (int ni = 0; ni < 4; ++ni) {
        int row = m0 + wm + mi * 16 + quad * 4;
        int col = n0 - 2048 + wn + ni * 16 + l16;
#pragma unroll
        for (int r = 0; r < 4; ++r)
          Cc[(size_t)(row + r) * 128 + col] = f2b(acc[mi][ni][r]);
      }
  }
}

// ------- fused GEMM #2: [k_c(acc->ksb) | v_c -> Vt direct] ---------------
__global__ __launch_bounds__(256) void gemm_fused2(
    const unsigned short* __restrict__ A, const unsigned short* __restrict__ Bt,
    unsigned short* __restrict__ Ck, unsigned short* __restrict__ vt, int K) {
  __shared__ unsigned short As[2][1024 * 8];
  __shared__ unsigned short Bs[2][1024 * 8];
  const int tid = threadIdx.x;
  const int id = blockIdx.x;
  const int swz = (id & 7) * 64 + (id >> 3);          // 512 = 8*64 bijective
  const int m0 = (swz >> 4) * 128, n0 = (swz & 15) * 128;
  const int wave = tid >> 6, lane = tid & 63;
  const int wm = (wave >> 1) * 64, wn = (wave & 1) * 64;
  const int l16 = lane & 15, quad = lane >> 4;

  f32x4 acc[4][4];
#pragma unroll
  for (int i = 0; i < 4; ++i)
#pragma unroll
    for (int j = 0; j < 4; ++j)
#pragma unroll
      for (int r = 0; r < 4; ++r) acc[i][j][r] = 0.f;

  auto stage = [&](int k0, int b) {
#pragma unroll
    for (int it = 0; it < 4; ++it) {
      int c = it * 256 + tid;
      int m = c >> 3, kc = (c & 7) ^ (m & 7);
      g2lds16(&A[(size_t)(m0 + m) * K + k0 + kc * 8], &As[b][c * 8]);
    }
#pragma unroll
    for (int it = 0; it < 4; ++it) {
      int c = it * 256 + tid;
      int n = c >> 3, kc = (c & 7) ^ (n & 7);
      g2lds16(&Bt[(size_t)(n0 + n) * K + k0 + kc * 8], &Bs[b][c * 8]);
    }
  };

  const int T = K / 64;
  stage(0, 0);
  for (int t = 0; t < T; ++t) {
    __builtin_amdgcn_s_barrier();
    asm volatile("" ::: "memory");
    if (t + 1 < T) {
      stage((t + 1) * 64, (t + 1) & 1);
      asm volatile("s_waitcnt vmcnt(8)" ::: "memory");
    } else {
      asm volatile("s_waitcnt vmcnt(0)" ::: "memory");
    }
    __builtin_amdgcn_s_barrier();
    asm volatile("" ::: "memory");
    const int cb = t & 1;

#pragma unroll
    for (int ks = 0; ks < 2; ++ks) {
      bf16x8 af[4], bfr[4];
#pragma unroll
      for (int mi = 0; mi < 4; ++mi) {
        int m = wm + mi * 16 + l16;
        af[mi] = *reinterpret_cast<const bf16x8*>(
            &As[cb][(m * 8 + ((ks * 4 + quad) ^ (m & 7))) * 8]);
      }
#pragma unroll
      for (int ni = 0; ni < 4; ++ni) {
        int n = wn + ni * 16 + l16;
        bfr[ni] = *reinterpret_cast<const bf16x8*>(
            &Bs[cb][(n * 8 + ((ks * 4 + quad) ^ (n & 7))) * 8]);
      }
#pragma unroll
      for (int mi = 0; mi < 4; ++mi)
#pragma unroll
        for (int ni = 0; ni < 4; ++ni)
          acc[mi][ni] = __builtin_amdgcn_mfma_f32_16x16x32_bf16(
              af[mi], bfr[ni], acc[mi][ni], 0, 0, 0);
    }
  }

  if (n0 < 1024) {
    // k_c: accumulate onto rope'd k_r
#pragma unroll
    for (int mi = 0; mi < 4; ++mi)
#pragma unroll
      for (int ni = 0; ni < 4; ++ni) {
        int row = m0 + wm + mi * 16 + quad * 4;
        int col = n0 + wn + ni * 16 + l16;
#pragma unroll
        for (int r = 0; r < 4; ++r) {
          size_t idx = (size_t)(row + r) * 1024 + col;
          Ck[idx] = f2b(acc[mi][ni][r] + b2f(Ck[idx]));
        }
      }
  } else {
    // v_c -> Vt[b,h,d,sigma^-1(l)] direct, 8B stores
    const int L = 2048;
#pragma unroll
    for (int mi = 0; mi < 4; ++mi)
#pragma unroll
      for (int ni = 0; ni < 4; ++ni) {
        int row = m0 + wm + mi * 16 + quad * 4;       // row % 4 == 0
        int col = n0 - 1024 + wn + ni * 16 + l16;     // h*64 + d
        int l = row & (L - 1);
        int bh = ((row >> 11) << 4) | (col >> 6);
        int d = col & 63;
        int s = (l & ~63) | (((l >> 5) & 1) << 5) | (((l >> 3) & 1) << 4) |
                (((l >> 2) & 1) << 3) | (((l >> 4) & 1) << 2);
        ushort4v w;
#pragma unroll
        for (int r = 0; r < 4; ++r) w[r] = f2b(acc[mi][ni][r]);
        *reinterpret_cast<ushort4v*>(
            &vt[(size_t)bh * 64 * L + (size_t)d * L + s]) = w;
      }
  }
}

// ---------- flash v18: KVBLK=128, dbuf + counted vmcnt, setprio on PV -----
// flash17 machinery with 128 keys per step: T = 16 steps (half the barrier
// pairs), per-step MFMA doubles (72). QK^T computed per 64-key group (st
// transient 32 VGPR). V staged with per-64-group sigma pre-swizzle on the
// GLOBAL source (linear LDS dest, rule #21). LDS 64KB -> 2 blocks/CU (grid
// caps at 2/CU anyway). s_setprio(1) wraps the PV MFMA cluster (T5 -- the
// counted-vmcnt schedule has wave role-split, the regime where it pays).
__global__ __launch_bounds__(256, 2) void flash18_kernel(
    const unsigned short* __restrict__ qs, const unsigned short* __restrict__ ks,
    const unsigned short* __restrict__ vt, unsigned short* __restrict__ o,
    int L) {
  __shared__ unsigned short Ks[2][1024 * 8];  // 128 key x 64 d, swizzled
  __shared__ unsigned short Vs[2][1024 * 8];  // 64 d x 128 key(perm), swizzled
  const int tid = threadIdx.x;
  const int wave = tid >> 6, lane = tid & 63;
  const int l16 = lane & 15, quad = lane >> 4;
  const int bh = blockIdx.y;                   // b*16 + h
  const int qb = blockIdx.x * 128 + wave * 32; // this wave's 32 q rows
  const size_t base = ((size_t)(bh >> 4) * L) * 1024 + (bh & 15) * 64;
  const size_t vtbase = (size_t)bh * 64 * L;

  bf16x8 aq[2][2];
#pragma unroll
  for (int mt = 0; mt < 2; ++mt) {
    size_t qrow = base + (size_t)(qb + mt * 16 + l16) * 1024;
    aq[mt][0] = *reinterpret_cast<const bf16x8*>(&qs[qrow + quad * 8]);
    aq[mt][1] = *reinterpret_cast<const bf16x8*>(&qs[qrow + 32 + quad * 8]);
  }

  ushort8v onesu;
#pragma unroll
  for (int j = 0; j < 8; ++j) onesu[j] = 0x3F80;  // bf16 1.0
  bf16x8 ones = *reinterpret_cast<bf16x8*>(&onesu);

  f32x4 oacc[2][4];
  f32x4 lacc[2];
#pragma unroll
  for (int mt = 0; mt < 2; ++mt) {
#pragma unroll
    for (int r = 0; r < 4; ++r) lacc[mt][r] = 0.f;
#pragma unroll
    for (int nt = 0; nt < 4; ++nt)
#pragma unroll
      for (int r = 0; r < 4; ++r) oacc[mt][nt][r] = 0.f;
  }

  auto stage = [&](int t, int b) {
    int k0 = t * 128;
#pragma unroll
    for (int it = 0; it < 4; ++it) {
      int c = it * 256 + tid;                  // [0,1024)
      int key = c >> 3, dc = (c & 7) ^ (key & 7);
      g2lds16(&ks[base + (size_t)(k0 + key) * 1024 + dc * 8], &Ks[b][c * 8]);
    }
#pragma unroll
    for (int it = 0; it < 4; ++it) {
      int c = it * 256 + tid;                  // [0,1024)
      int d = c >> 4, oc = c & 15;             // d in [0,64), oc = key octet
      int g = oc >> 3, oo = oc & 7;            // 64-key group, octet in group
      int kcs = g * 8 + (oo ^ (d & 7));        // pre-swizzled source octet
      g2lds16(&vt[vtbase + (size_t)d * L + k0 + kcs * 8], &Vs[b][c * 8]);
    }
  };

  const int T = L / 128;                       // 16 steps
  stage(0, 0);

  for (int t = 0; t < T; ++t) {
    __builtin_amdgcn_s_barrier();            // compute(t-1) done; buf free
    asm volatile("" ::: "memory");
    if (t + 1 < T) {
      stage(t + 1, (t + 1) & 1);
      asm volatile("s_waitcnt vmcnt(8)" ::: "memory");  // tile t resident
    } else {
      asm volatile("s_waitcnt vmcnt(0)" ::: "memory");
    }
    __builtin_amdgcn_s_barrier();            // tile t visible to all
    asm volatile("" ::: "memory");

    const int cb = t & 1;
    const unsigned short* Kb = &Ks[cb][0];
    const unsigned short* Vb = &Vs[cb][0];

    // QK^T + exp2 + sigma-renaming per 64-key group (st stays transient)
    bf16x8 ap[2][4];                         // [mt][key-slot of 32]
#pragma unroll
    for (int g = 0; g < 2; ++g) {
      f32x4 st[2][4];
#pragma unroll
      for (int nt4 = 0; nt4 < 4; ++nt4) {
        int key = (g * 4 + nt4) * 16 + l16;
        int dc0 = quad ^ (key & 7);
        int dc1 = (4 + quad) ^ (key & 7);
        bf16x8 bk0 = *reinterpret_cast<const bf16x8*>(
            &Kb[(key * 8 + dc0) * 8]);
        bf16x8 bk1 = *reinterpret_cast<const bf16x8*>(
            &Kb[(key * 8 + dc1) * 8]);
#pragma unroll
        for (int mt = 0; mt < 2; ++mt) {
          f32x4 z; z[0] = z[1] = z[2] = z[3] = 0.f;
          z = __builtin_amdgcn_mfma_f32_16x16x32_bf16(bk0, aq[mt][0], z, 0, 0, 0);
          z = __builtin_amdgcn_mfma_f32_16x16x32_bf16(bk1, aq[mt][1], z, 0, 0, 0);
          st[mt][nt4] = z;
        }
      }
#pragma unroll
      for (int mt = 0; mt < 2; ++mt)
#pragma unroll
        for (int hfg = 0; hfg < 2; ++hfg) {
          int kf = g * 2 + hfg;
#pragma unroll
          for (int w = 0; w < 4; ++w) {
            int nt4 = 2 * hfg + (w >> 1), p = w & 1;
            ap[mt][kf][2 * w] =
                (__bf16)__builtin_amdgcn_exp2f(st[mt][nt4][2 * p]);
            ap[mt][kf][2 * w + 1] =
                (__bf16)__builtin_amdgcn_exp2f(st[mt][nt4][2 * p + 1]);
          }
          lacc[mt] = __builtin_amdgcn_mfma_f32_16x16x32_bf16(
              ap[mt][kf], ones, lacc[mt], 0, 0, 0);
        }
    }

    // O += P V over 128 keys (4 key-slots), V fragments shared by both mt
    __builtin_amdgcn_s_setprio(1);
#pragma unroll
    for (int nt = 0; nt < 4; ++nt) {
      int d = nt * 16 + l16;
#pragma unroll
      for (int kf = 0; kf < 4; ++kf) {
        int kc = (kf >> 1) * 8 + (((kf & 1) * 4 + quad) ^ (d & 7));
        bf16x8 bv = *reinterpret_cast<const bf16x8*>(
            &Vb[(d * 16 + kc) * 8]);
#pragma unroll
        for (int mt = 0; mt < 2; ++mt)
          oacc[mt][nt] = __builtin_amdgcn_mfma_f32_16x16x32_bf16(
              ap[mt][kf], bv, oacc[mt][nt], 0, 0, 0);
      }
    }
    __builtin_amdgcn_s_setprio(0);
  }

#pragma unroll
  for (int mt = 0; mt < 2; ++mt)
#pragma unroll
    for (int r = 0; r < 4; ++r) {
      float inv = __builtin_amdgcn_rcpf(lacc[mt][r]);
      int q = qb + mt * 16 + quad * 4 + r;
#pragma unroll
      for (int nt = 0; nt < 4; ++nt)
        o[base + (size_t)q * 1024 + nt * 16 + l16] =
            f2b(oacc[mt][nt][r] * inv);
    }
}

// ---------------- driver ----------------
extern "C" void kernel_launch(void* const* d_in, const int* in_sizes, int n_in,
                              void* d_out, int out_size, void* d_ws, size_t ws_size,
                              hipStream_t stream) {
  const float* X    = (const float*)d_in[0];
  const float* tq   = (const float*)d_in[1];
  const float* tk   = (const float*)d_in[2];
  const float* wkvc = (const float*)d_in[3];
  const float* wkc  = (const float*)d_in[4];
  const float* wvc  = (const float*)d_in[5];
  const float* wqr  = (const float*)d_in[6];
  const float* wkr  = (const float*)d_in[7];
  const float* wo   = (const float*)d_in[8];

  const int D = 1024, DC = 128, L = 2048;
  const int M = in_sizes[0] / D;       // B*L
  const int B = M / L;
  const int NBH = B * 16;
  (void)n_in; (void)out_size; (void)ws_size;

  unsigned short* p = (unsigned short*)d_ws;
  auto take = [&](size_t n) { unsigned short* r = p; p += n; return r; };
  unsigned short* Xb    = take((size_t)M * D);
  unsigned short* qsb   = take((size_t)M * D);
  unsigned short* ksb   = take((size_t)M * D);
  unsigned short* vcb   = take((size_t)M * D);
  unsigned short* ckv   = take((size_t)M * DC);
  unsigned short* Wbig  = take((size_t)(2 * D + DC) * D);   // [wqr|wkr|wkvc]^T
  unsigned short* Wkcvc = take((size_t)(2 * D) * DC);       // [wkc|wvc]^T
  unsigned short* WoT   = take((size_t)D * D);
  f32x2* ctab = (f32x2*)take((size_t)M * 32 * 4);           // M*32 float2
  unsigned short* vtb   = Xb;   // Xb dead after fused3 gemm; fused2 writes Vt
  unsigned short* obuf  = vcb;  // flash O lands here

  // prep: cvt + all 6 weight transposes + rope cos table in ONE launch
  const int n8 = M * D / 8;
  const int cvtb = (n8 + 255) / 256;
  const int ropeb = M / 8;             // M*32 threads / 256
  prep_kernel<<<cvtb + 864 + ropeb, 256, 0, stream>>>(
      X, Xb, cvtb, n8,
      wqr,  Wbig,
      wkr,  Wbig + (size_t)D * D,
      wkvc, Wbig + (size_t)2 * D * D,
      wkc,  Wkcvc,
      wvc,  Wkcvc + (size_t)D * DC,
      wo,   WoT,
      tq, tk, ctab);

  {
    // 1D grid 17*32 = 544 = 8*68, XCD-chunk-swizzled in-kernel
    gemm_fused3<<<(2 * D + DC) / 128 * (M / 128), 256, 0, stream>>>(
        Xb, Wbig, qsb, ksb, ckv, ctab, D);
  }
  {
    // 1D grid 16*32 = 512 = 8*64, XCD-chunk-swizzled in-kernel
    gemm_fused2<<<(2 * D / 128) * (M / 128), 256, 0, stream>>>(
        ckv, Wkcvc, ksb, vtb, DC);
  }

  dim3 fg(L / 128, NBH);                                   // (16, 32)
  flash18_kernel<<<fg, 256, 0, stream>>>(qsb, ksb, vtb, obuf, L);

  {
    // 1D grid (D/128)*(M/64) = 8*64 = 512 = 2 blocks/CU, swizzled
    gemm_bt<64, float, false><<<(D / 128) * (M / 64), 256, 0, stream>>>(
        obuf, WoT, (float*)d_out, M, D, D);
  }
}